// Round 2
// baseline (1820.704 us; speedup 1.0000x reference)
//
#include <hip/hip_runtime.h>
#include <cstdint>

#define EPSV 1e-5f

// ---------------------------------------------------------------------------
// Generic tiled fp32 GEMM: C[M,N] = A[M,K] @ B[K,N] + bias
// MODE 0: A = direct row-major
// MODE 1: A row r, col k -> cate_table[cate[r*4 + (k>>8)]][k&255]
// MODE 2: A row r -> src[gidx[r]*K + k]   (row gather)
// ---------------------------------------------------------------------------
template<int MODE>
__global__ __launch_bounds__(256) void gemm_k(
    int M, int N, int K,
    const float* __restrict__ A,
    const int*   __restrict__ gidx,
    const float* __restrict__ table,
    const float* __restrict__ Bm,
    const float* __restrict__ bias,
    float* __restrict__ C)
{
    __shared__ float As[16][65];
    __shared__ float Bs[16][64];
    const int tid = threadIdx.x;
    const int bm = blockIdx.x * 64;
    const int bn = blockIdx.y * 64;
    const int tx = tid & 15, ty = tid >> 4;
    const int a_row = tid >> 2;          // 0..63
    const int a_k4  = (tid & 3) * 4;     // 0,4,8,12
    const int b_k   = tid >> 4;          // 0..15
    const int b_n4  = (tid & 15) * 4;    // 0..60
    float acc[4][4] = {};

    for (int kt = 0; kt < K; kt += 16) {
        float4 av;
        int grow = bm + a_row;
        int gk = kt + a_k4;
        if (MODE == 0) {
            av = *reinterpret_cast<const float4*>(A + (size_t)grow * K + gk);
        } else if (MODE == 1) {
            int g = gk >> 8, e = gk & 255;
            int idx = gidx[grow * 4 + g];
            av = *reinterpret_cast<const float4*>(table + (size_t)idx * 256 + e);
        } else {
            int srow = gidx[grow];
            av = *reinterpret_cast<const float4*>(A + (size_t)srow * K + gk);
        }
        As[a_k4 + 0][a_row] = av.x;
        As[a_k4 + 1][a_row] = av.y;
        As[a_k4 + 2][a_row] = av.z;
        As[a_k4 + 3][a_row] = av.w;
        float4 bv = *reinterpret_cast<const float4*>(Bm + (size_t)(kt + b_k) * N + bn + b_n4);
        *reinterpret_cast<float4*>(&Bs[b_k][b_n4]) = bv;
        __syncthreads();
        #pragma unroll
        for (int kk = 0; kk < 16; ++kk) {
            float a0 = As[kk][ty*4+0], a1 = As[kk][ty*4+1],
                  a2 = As[kk][ty*4+2], a3 = As[kk][ty*4+3];
            float b0 = Bs[kk][tx*4+0], b1 = Bs[kk][tx*4+1],
                  b2 = Bs[kk][tx*4+2], b3 = Bs[kk][tx*4+3];
            acc[0][0] += a0*b0; acc[0][1] += a0*b1; acc[0][2] += a0*b2; acc[0][3] += a0*b3;
            acc[1][0] += a1*b0; acc[1][1] += a1*b1; acc[1][2] += a1*b2; acc[1][3] += a1*b3;
            acc[2][0] += a2*b0; acc[2][1] += a2*b1; acc[2][2] += a2*b2; acc[2][3] += a2*b3;
            acc[3][0] += a3*b0; acc[3][1] += a3*b1; acc[3][2] += a3*b2; acc[3][3] += a3*b3;
        }
        __syncthreads();
    }
    #pragma unroll
    for (int i = 0; i < 4; ++i) {
        int r = bm + ty*4 + i;
        #pragma unroll
        for (int j = 0; j < 4; ++j) {
            int c = bn + tx*4 + j;
            C[(size_t)r * N + c] = acc[i][j] + bias[c];
        }
    }
}

// ---------------------------------------------------------------------------
// LayerNorm over H=256, wave per row. Optional +pos_emb (row%1024) and leaky.
// ---------------------------------------------------------------------------
__global__ __launch_bounds__(256) void ln_k(
    int M, const float* __restrict__ X,
    const float* __restrict__ g, const float* __restrict__ b,
    float* __restrict__ Y, int ldY, int colOff,
    int do_leaky, const float* __restrict__ pos)
{
    int wid = (blockIdx.x * 256 + threadIdx.x) >> 6;
    int lane = threadIdx.x & 63;
    if (wid >= M) return;
    const float* x = X + (size_t)wid * 256;
    float v[4]; float s = 0.f;
    #pragma unroll
    for (int j = 0; j < 4; ++j) { v[j] = x[lane + 64*j]; s += v[j]; }
    #pragma unroll
    for (int o = 32; o; o >>= 1) s += __shfl_xor(s, o);
    float mu = s * (1.0f/256.0f);
    float q = 0.f;
    #pragma unroll
    for (int j = 0; j < 4; ++j) { float d = v[j]-mu; q += d*d; }
    #pragma unroll
    for (int o = 32; o; o >>= 1) q += __shfl_xor(q, o);
    float rstd = rsqrtf(q*(1.0f/256.0f) + EPSV);
    #pragma unroll
    for (int j = 0; j < 4; ++j) {
        int c = lane + 64*j;
        float y = (v[j]-mu)*rstd*g[c] + b[c];
        if (pos) y += pos[(size_t)(wid & 1023) * 256 + c];
        if (do_leaky) y = (y >= 0.f) ? y : 0.01f*y;
        Y[(size_t)wid * ldY + colOff + c] = y;
    }
}

// ---------------------------------------------------------------------------
// BatchNorm statistics: stats[0..7]=sum, [8..15]=sumsq
// ---------------------------------------------------------------------------
__global__ __launch_bounds__(256) void bn_stats_k(const float* __restrict__ cont,
                                                  float* __restrict__ stats)
{
    __shared__ float ss[8], sq[8];
    int tid = threadIdx.x;
    if (tid < 8) { ss[tid] = 0.f; sq[tid] = 0.f; }
    __syncthreads();
    int gt = blockIdx.x * 256 + tid;
    float s = 0.f, q = 0.f;
    for (int e = gt; e < 32768*8; e += 256*256) { float v = cont[e]; s += v; q += v*v; }
    int f = gt & 7;
    atomicAdd(&ss[f], s);
    atomicAdd(&sq[f], q);
    __syncthreads();
    if (tid < 8) { atomicAdd(&stats[tid], ss[tid]); atomicAdd(&stats[8+tid], sq[tid]); }
}

// ---------------------------------------------------------------------------
// cont path fully fused: BN-normalize + (8x256 GEMM) + bias + LN + leaky
// ---------------------------------------------------------------------------
__global__ __launch_bounds__(256) void cont_k(
    const float* __restrict__ cont, const float* __restrict__ stats,
    const float* __restrict__ bn_g, const float* __restrict__ bn_b,
    const float* __restrict__ W, const float* __restrict__ bias,
    const float* __restrict__ g, const float* __restrict__ bL,
    float* __restrict__ seq3)
{
    __shared__ float Ws[8][256];
    __shared__ float sscale[8], sshift[8];
    __shared__ float cr[8];
    __shared__ float red[8];
    int tid = threadIdx.x;
    #pragma unroll
    for (int d = 0; d < 8; ++d) Ws[d][tid] = W[d*256 + tid];
    if (tid < 8) {
        float mean = stats[tid] * (1.0f/32768.0f);
        float var  = stats[8+tid] * (1.0f/32768.0f) - mean*mean;
        float r = rsqrtf(var + EPSV);
        float sc = r * bn_g[tid];
        sscale[tid] = sc;
        sshift[tid] = bn_b[tid] - mean*sc;
    }
    __syncthreads();
    int lane = tid & 63, wv = tid >> 6;
    float gv = g[tid], bv = bL[tid], biasv = bias[tid];
    for (int row = blockIdx.x; row < 32768; row += gridDim.x) {
        if (tid < 8) cr[tid] = cont[(size_t)row*8 + tid]*sscale[tid] + sshift[tid];
        __syncthreads();
        float acc = biasv;
        #pragma unroll
        for (int d = 0; d < 8; ++d) acc += cr[d]*Ws[d][tid];
        float s = acc;
        #pragma unroll
        for (int o = 32; o; o >>= 1) s += __shfl_xor(s, o);
        if (lane == 0) red[wv] = s;
        __syncthreads();
        float mu = (red[0]+red[1]+red[2]+red[3]) * (1.0f/256.0f);
        float dc = acc - mu;
        float qv = dc*dc;
        #pragma unroll
        for (int o = 32; o; o >>= 1) qv += __shfl_xor(qv, o);
        if (lane == 0) red[4+wv] = qv;
        __syncthreads();
        float var = (red[4]+red[5]+red[6]+red[7]) * (1.0f/256.0f);
        float y = dc * rsqrtf(var + EPSV) * gv + bv;
        y = (y >= 0.f) ? y : 0.01f*y;
        seq3[(size_t)row*768 + 512 + tid] = y;
        __syncthreads();
    }
}

// ---------------------------------------------------------------------------
// key-index construction
// ---------------------------------------------------------------------------
__global__ void build_maps_k(const int* __restrict__ qidx, int* __restrict__ kmap)
{
    __shared__ int flag[1024];
    __shared__ int scan[1024];
    int t = threadIdx.x;
    flag[t] = 0;
    __syncthreads();
    if (t < 128) flag[qidx[t]] = 1;
    __syncthreads();
    int nq = 1 - flag[t];
    scan[t] = nq;
    __syncthreads();
    for (int off = 1; off < 1024; off <<= 1) {
        int v = (t >= off) ? scan[t - off] : 0;
        __syncthreads();
        scan[t] += v;
        __syncthreads();
    }
    if (nq) kmap[scan[t] - 1] = t;
}

__global__ void expand_maps_k(const int* __restrict__ qidx, const int* __restrict__ kmap,
                              int* __restrict__ qmap, int* __restrict__ krmap)
{
    int i = blockIdx.x * 256 + threadIdx.x;
    if (i < 32*128) { int b = i >> 7; int t = i & 127; qmap[i] = b*1024 + qidx[t]; }
    if (i < 32*896) { int b = i / 896; int t = i - b*896; krmap[i] = b*1024 + kmap[t]; }
}

// ---------------------------------------------------------------------------
// mask dtype sniff + canonicalize to uint8[28672].
// Probes only the first 28672 bytes (minimum possible buffer size):
//   any nonzero byte at i%4!=0            -> source is uint8/bool
//   else any nonzero byte at i%8==4       -> source is int32
//   else                                  -> source is int64
// ---------------------------------------------------------------------------
__global__ void mask_prep_k(const unsigned char* __restrict__ msrc,
                            unsigned char* __restrict__ mu8)
{
    __shared__ int f_u8, f_i32;
    int t = threadIdx.x;
    if (t == 0) { f_u8 = 0; f_i32 = 0; }
    __syncthreads();
    int lu8 = 0, li32 = 0;
    for (int i = t; i < 28672; i += 256) {
        unsigned char v = msrc[i];
        if (v) {
            if (i & 3) lu8 = 1;
            else if ((i & 7) == 4) li32 = 1;
        }
    }
    if (lu8) atomicOr(&f_u8, 1);
    if (li32) atomicOr(&f_i32, 1);
    __syncthreads();
    int mode = f_u8 ? 0 : (f_i32 ? 1 : 2);
    for (int i = t; i < 28672; i += 256) {
        unsigned char v;
        if (mode == 0)      v = msrc[i] ? 1 : 0;
        else if (mode == 1) v = ((const int*)msrc)[i] ? 1 : 0;
        else                v = ((const long long*)msrc)[i] ? 1 : 0;
        mu8[i] = v;
    }
}

// ---------------------------------------------------------------------------
// attention: wave per (b,h,q) row. LQ=128, LK=896, DH=32, NH=8
// ---------------------------------------------------------------------------
__global__ __launch_bounds__(256) void attn_k(
    const float* __restrict__ Q, const float* __restrict__ Kb, const float* __restrict__ Vb,
    const unsigned char* __restrict__ mask, float* __restrict__ out)
{
    __shared__ float Qs[4][32];
    __shared__ float Ps[4][896];
    int wv = threadIdx.x >> 6;
    int lane = threadIdx.x & 63;
    int gw = blockIdx.x * 4 + wv;     // (b*8 + h)*128 + q
    int q = gw & 127;
    int h = (gw >> 7) & 7;
    int b = gw >> 10;
    const float* qrow = Q + ((size_t)(b*128 + q))*256 + h*32;
    if (lane < 32) Qs[wv][lane] = qrow[lane];
    __syncthreads();
    const float* Kbase = Kb + ((size_t)(b*896))*256 + h*32;
    const unsigned char* mrow = mask + b*896;
    float sc[14];
    float mx = -3.0e38f;
    #pragma unroll
    for (int j = 0; j < 14; ++j) {
        int k = lane + 64*j;
        const float* kr = Kbase + (size_t)k*256;
        float acc = 0.f;
        #pragma unroll
        for (int d = 0; d < 32; ++d) acc += Qs[wv][d]*kr[d];
        float s = mrow[k] ? -1e9f : acc*0.17677669529663687f;  // 1/sqrt(32)
        sc[j] = s;
        mx = fmaxf(mx, s);
    }
    #pragma unroll
    for (int o = 32; o; o >>= 1) mx = fmaxf(mx, __shfl_xor(mx, o));
    float sm = 0.f;
    float p[14];
    #pragma unroll
    for (int j = 0; j < 14; ++j) { p[j] = __expf(sc[j]-mx); sm += p[j]; }
    #pragma unroll
    for (int o = 32; o; o >>= 1) sm += __shfl_xor(sm, o);
    float inv = 1.0f / sm;
    #pragma unroll
    for (int j = 0; j < 14; ++j) Ps[wv][lane + 64*j] = p[j]*inv;
    __syncthreads();
    int d = lane & 31, half = lane >> 5;
    const float* Vbase = Vb + ((size_t)(b*896))*256 + h*32 + d;
    float acc = 0.f;
    for (int k = half*448; k < half*448 + 448; ++k)
        acc += Ps[wv][k] * Vbase[(size_t)k*256];
    acc += __shfl_xor(acc, 32);
    if (lane < 32) out[((size_t)(b*128 + q))*256 + h*32 + d] = acc;
}

// ---------------------------------------------------------------------------
extern "C" void kernel_launch(void* const* d_in, const int* in_sizes, int n_in,
                              void* d_out, int out_size, void* d_ws, size_t ws_size,
                              hipStream_t stream)
{
    const float* node       = (const float*)d_in[0];
    const int*   cate       = (const int*)d_in[1];
    const float* cont       = (const float*)d_in[2];
    const int*   qidx       = (const int*)d_in[3];
    const unsigned char* mask = (const unsigned char*)d_in[4];
    const float* cate_table = (const float*)d_in[5];
    const float* pos_emb    = (const float*)d_in[6];
    const float* node_W     = (const float*)d_in[7];
    const float* node_b     = (const float*)d_in[8];
    const float* node_ln_g  = (const float*)d_in[9];
    const float* node_ln_b  = (const float*)d_in[10];
    const float* cate_W     = (const float*)d_in[11];
    const float* cate_b     = (const float*)d_in[12];
    const float* cate_ln_g  = (const float*)d_in[13];
    const float* cate_ln_b  = (const float*)d_in[14];
    const float* bn_g       = (const float*)d_in[15];
    const float* bn_b       = (const float*)d_in[16];
    const float* cont_W     = (const float*)d_in[17];
    const float* cont_b     = (const float*)d_in[18];
    const float* cont_ln_g  = (const float*)d_in[19];
    const float* cont_ln_b  = (const float*)d_in[20];
    const float* comb_W     = (const float*)d_in[21];
    const float* comb_b     = (const float*)d_in[22];
    const float* comb_ln_g  = (const float*)d_in[23];
    const float* comb_ln_b  = (const float*)d_in[24];
    const float* q_W        = (const float*)d_in[25];
    const float* q_b        = (const float*)d_in[26];
    const float* k_W        = (const float*)d_in[27];
    const float* k_b        = (const float*)d_in[28];
    const float* v_W        = (const float*)d_in[29];
    const float* v_b        = (const float*)d_in[30];
    const float* reg_W1     = (const float*)d_in[31];
    const float* reg_b1     = (const float*)d_in[32];
    const float* reg_ln_g   = (const float*)d_in[33];
    const float* reg_ln_b   = (const float*)d_in[34];
    const float* reg_W2     = (const float*)d_in[35];
    const float* reg_b2     = (const float*)d_in[36];

    char* ws = (char*)d_ws;
    float* seq3 = (float*)(ws + 0);            // 32768*768*4
    float* tmp  = (float*)(ws + 100663296);    // 32768*256*4
    float* seq  = (float*)(ws + 134217728);    // 32768*256*4
    // seq3 region recycled after comb GEMM:
    float* Qb   = (float*)(ws + 0);
    float* Kb   = (float*)(ws + 4194304);
    float* Vb   = (float*)(ws + 33554432);
    float* AO   = (float*)(ws + 62914560);
    float* Hb   = (float*)(ws + 67108864);
    float* stats= (float*)(ws + 167772160);
    int*   kmap = (int*)  (ws + 167772224);
    int*   qmap = (int*)  (ws + 167775808);
    int*   krmap= (int*)  (ws + 167792192);
    unsigned char* mu8 = (unsigned char*)(ws + 167907328);
    float* outp = (float*)d_out;

    hipMemsetAsync(stats, 0, 64, stream);
    bn_stats_k<<<256, 256, 0, stream>>>(cont, stats);
    mask_prep_k<<<1, 256, 0, stream>>>(mask, mu8);

    // node path
    gemm_k<0><<<dim3(512,4), 256, 0, stream>>>(32768,256,1024, node, nullptr, nullptr, node_W, node_b, tmp);
    ln_k<<<8192,256,0,stream>>>(32768, tmp, node_ln_g, node_ln_b, seq3, 768, 0, 1, nullptr);
    // cate path
    gemm_k<1><<<dim3(512,4), 256, 0, stream>>>(32768,256,1024, nullptr, cate, cate_table, cate_W, cate_b, tmp);
    ln_k<<<8192,256,0,stream>>>(32768, tmp, cate_ln_g, cate_ln_b, seq3, 768, 256, 1, nullptr);
    // cont path
    cont_k<<<2048,256,0,stream>>>(cont, stats, bn_g, bn_b, cont_W, cont_b, cont_ln_g, cont_ln_b, seq3);
    // comb
    gemm_k<0><<<dim3(512,4),256,0,stream>>>(32768,256,768, seq3, nullptr, nullptr, comb_W, comb_b, tmp);
    ln_k<<<8192,256,0,stream>>>(32768, tmp, comb_ln_g, comb_ln_b, seq, 256, 0, 0, pos_emb);
    // index maps
    build_maps_k<<<1,1024,0,stream>>>(qidx, kmap);
    expand_maps_k<<<112,256,0,stream>>>(qidx, kmap, qmap, krmap);
    // Q/K/V projections
    gemm_k<2><<<dim3(64,4),256,0,stream>>>(4096,256,256, seq, qmap, nullptr, q_W, q_b, Qb);
    gemm_k<2><<<dim3(448,4),256,0,stream>>>(28672,256,256, seq, krmap, nullptr, k_W, k_b, Kb);
    gemm_k<2><<<dim3(448,4),256,0,stream>>>(28672,256,256, seq, krmap, nullptr, v_W, v_b, Vb);
    // attention
    attn_k<<<8192,256,0,stream>>>(Qb, Kb, Vb, mu8, AO);
    // regression head
    gemm_k<0><<<dim3(64,4),256,0,stream>>>(4096,256,256, AO, nullptr, nullptr, reg_W1, reg_b1, tmp);
    ln_k<<<1024,256,0,stream>>>(4096, tmp, reg_ln_g, reg_ln_b, Hb, 256, 0, 1, nullptr);
    gemm_k<0><<<dim3(64,4),256,0,stream>>>(4096,256,256, Hb, nullptr, nullptr, reg_W2, reg_b2, outp);
}

// Round 3
// 1249.633 us; speedup vs baseline: 1.4570x; 1.4570x over previous
//
#include <hip/hip_runtime.h>
#include <cstdint>

#define EPSV 1e-5f

// ---------------------------------------------------------------------------
// Generic tiled fp32 GEMM: C[M,N] = A[M,K] @ B[K,N] + bias
// MODE 0: A = direct row-major
// MODE 1: A row r, col k -> cate_table[cate[r*4 + (k>>8)]][k&255]
// MODE 2: A row r -> src[gidx[r]*K + k]   (row gather)
// ---------------------------------------------------------------------------
template<int MODE>
__global__ __launch_bounds__(256) void gemm_k(
    int M, int N, int K,
    const float* __restrict__ A,
    const int*   __restrict__ gidx,
    const float* __restrict__ table,
    const float* __restrict__ Bm,
    const float* __restrict__ bias,
    float* __restrict__ C)
{
    __shared__ float As[16][65];
    __shared__ float Bs[16][64];
    const int tid = threadIdx.x;
    const int bm = blockIdx.x * 64;
    const int bn = blockIdx.y * 64;
    const int tx = tid & 15, ty = tid >> 4;
    const int a_row = tid >> 2;          // 0..63
    const int a_k4  = (tid & 3) * 4;     // 0,4,8,12
    const int b_k   = tid >> 4;          // 0..15
    const int b_n4  = (tid & 15) * 4;    // 0..60
    float acc[4][4] = {};

    for (int kt = 0; kt < K; kt += 16) {
        float4 av;
        int grow = bm + a_row;
        int gk = kt + a_k4;
        if (MODE == 0) {
            av = *reinterpret_cast<const float4*>(A + (size_t)grow * K + gk);
        } else if (MODE == 1) {
            int g = gk >> 8, e = gk & 255;
            int idx = gidx[grow * 4 + g];
            av = *reinterpret_cast<const float4*>(table + (size_t)idx * 256 + e);
        } else {
            int srow = gidx[grow];
            av = *reinterpret_cast<const float4*>(A + (size_t)srow * K + gk);
        }
        As[a_k4 + 0][a_row] = av.x;
        As[a_k4 + 1][a_row] = av.y;
        As[a_k4 + 2][a_row] = av.z;
        As[a_k4 + 3][a_row] = av.w;
        float4 bv = *reinterpret_cast<const float4*>(Bm + (size_t)(kt + b_k) * N + bn + b_n4);
        *reinterpret_cast<float4*>(&Bs[b_k][b_n4]) = bv;
        __syncthreads();
        #pragma unroll
        for (int kk = 0; kk < 16; ++kk) {
            float a0 = As[kk][ty*4+0], a1 = As[kk][ty*4+1],
                  a2 = As[kk][ty*4+2], a3 = As[kk][ty*4+3];
            float b0 = Bs[kk][tx*4+0], b1 = Bs[kk][tx*4+1],
                  b2 = Bs[kk][tx*4+2], b3 = Bs[kk][tx*4+3];
            acc[0][0] += a0*b0; acc[0][1] += a0*b1; acc[0][2] += a0*b2; acc[0][3] += a0*b3;
            acc[1][0] += a1*b0; acc[1][1] += a1*b1; acc[1][2] += a1*b2; acc[1][3] += a1*b3;
            acc[2][0] += a2*b0; acc[2][1] += a2*b1; acc[2][2] += a2*b2; acc[2][3] += a2*b3;
            acc[3][0] += a3*b0; acc[3][1] += a3*b1; acc[3][2] += a3*b2; acc[3][3] += a3*b3;
        }
        __syncthreads();
    }
    #pragma unroll
    for (int i = 0; i < 4; ++i) {
        int r = bm + ty*4 + i;
        #pragma unroll
        for (int j = 0; j < 4; ++j) {
            int c = bn + tx*4 + j;
            C[(size_t)r * N + c] = acc[i][j] + bias[c];
        }
    }
}

// ---------------------------------------------------------------------------
// LayerNorm over H=256, wave per row. Optional +pos_emb (row%1024) and leaky.
// ---------------------------------------------------------------------------
__global__ __launch_bounds__(256) void ln_k(
    int M, const float* __restrict__ X,
    const float* __restrict__ g, const float* __restrict__ b,
    float* __restrict__ Y, int ldY, int colOff,
    int do_leaky, const float* __restrict__ pos)
{
    int wid = (blockIdx.x * 256 + threadIdx.x) >> 6;
    int lane = threadIdx.x & 63;
    if (wid >= M) return;
    const float* x = X + (size_t)wid * 256;
    float v[4]; float s = 0.f;
    #pragma unroll
    for (int j = 0; j < 4; ++j) { v[j] = x[lane + 64*j]; s += v[j]; }
    #pragma unroll
    for (int o = 32; o; o >>= 1) s += __shfl_xor(s, o);
    float mu = s * (1.0f/256.0f);
    float q = 0.f;
    #pragma unroll
    for (int j = 0; j < 4; ++j) { float d = v[j]-mu; q += d*d; }
    #pragma unroll
    for (int o = 32; o; o >>= 1) q += __shfl_xor(q, o);
    float rstd = rsqrtf(q*(1.0f/256.0f) + EPSV);
    #pragma unroll
    for (int j = 0; j < 4; ++j) {
        int c = lane + 64*j;
        float y = (v[j]-mu)*rstd*g[c] + b[c];
        if (pos) y += pos[(size_t)(wid & 1023) * 256 + c];
        if (do_leaky) y = (y >= 0.f) ? y : 0.01f*y;
        Y[(size_t)wid * ldY + colOff + c] = y;
    }
}

// ---------------------------------------------------------------------------
// BatchNorm statistics: stats[0..7]=sum, [8..15]=sumsq
// ---------------------------------------------------------------------------
__global__ __launch_bounds__(256) void bn_stats_k(const float* __restrict__ cont,
                                                  float* __restrict__ stats)
{
    __shared__ float ss[8], sq[8];
    int tid = threadIdx.x;
    if (tid < 8) { ss[tid] = 0.f; sq[tid] = 0.f; }
    __syncthreads();
    int gt = blockIdx.x * 256 + tid;
    float s = 0.f, q = 0.f;
    for (int e = gt; e < 32768*8; e += 256*256) { float v = cont[e]; s += v; q += v*v; }
    int f = gt & 7;
    atomicAdd(&ss[f], s);
    atomicAdd(&sq[f], q);
    __syncthreads();
    if (tid < 8) { atomicAdd(&stats[tid], ss[tid]); atomicAdd(&stats[8+tid], sq[tid]); }
}

// ---------------------------------------------------------------------------
// cont path fully fused: BN-normalize + (8x256 GEMM) + bias + LN + leaky
// ---------------------------------------------------------------------------
__global__ __launch_bounds__(256) void cont_k(
    const float* __restrict__ cont, const float* __restrict__ stats,
    const float* __restrict__ bn_g, const float* __restrict__ bn_b,
    const float* __restrict__ W, const float* __restrict__ bias,
    const float* __restrict__ g, const float* __restrict__ bL,
    float* __restrict__ seq3)
{
    __shared__ float Ws[8][256];
    __shared__ float sscale[8], sshift[8];
    __shared__ float cr[8];
    __shared__ float red[8];
    int tid = threadIdx.x;
    #pragma unroll
    for (int d = 0; d < 8; ++d) Ws[d][tid] = W[d*256 + tid];
    if (tid < 8) {
        float mean = stats[tid] * (1.0f/32768.0f);
        float var  = stats[8+tid] * (1.0f/32768.0f) - mean*mean;
        float r = rsqrtf(var + EPSV);
        float sc = r * bn_g[tid];
        sscale[tid] = sc;
        sshift[tid] = bn_b[tid] - mean*sc;
    }
    __syncthreads();
    int lane = tid & 63, wv = tid >> 6;
    float gv = g[tid], bv = bL[tid], biasv = bias[tid];
    for (int row = blockIdx.x; row < 32768; row += gridDim.x) {
        if (tid < 8) cr[tid] = cont[(size_t)row*8 + tid]*sscale[tid] + sshift[tid];
        __syncthreads();
        float acc = biasv;
        #pragma unroll
        for (int d = 0; d < 8; ++d) acc += cr[d]*Ws[d][tid];
        float s = acc;
        #pragma unroll
        for (int o = 32; o; o >>= 1) s += __shfl_xor(s, o);
        if (lane == 0) red[wv] = s;
        __syncthreads();
        float mu = (red[0]+red[1]+red[2]+red[3]) * (1.0f/256.0f);
        float dc = acc - mu;
        float qv = dc*dc;
        #pragma unroll
        for (int o = 32; o; o >>= 1) qv += __shfl_xor(qv, o);
        if (lane == 0) red[4+wv] = qv;
        __syncthreads();
        float var = (red[4]+red[5]+red[6]+red[7]) * (1.0f/256.0f);
        float y = dc * rsqrtf(var + EPSV) * gv + bv;
        y = (y >= 0.f) ? y : 0.01f*y;
        seq3[(size_t)row*768 + 512 + tid] = y;
        __syncthreads();
    }
}

// ---------------------------------------------------------------------------
// key-index construction
// ---------------------------------------------------------------------------
__global__ void build_maps_k(const int* __restrict__ qidx, int* __restrict__ kmap)
{
    __shared__ int flag[1024];
    __shared__ int scan[1024];
    int t = threadIdx.x;
    flag[t] = 0;
    __syncthreads();
    if (t < 128) flag[qidx[t]] = 1;
    __syncthreads();
    int nq = 1 - flag[t];
    scan[t] = nq;
    __syncthreads();
    for (int off = 1; off < 1024; off <<= 1) {
        int v = (t >= off) ? scan[t - off] : 0;
        __syncthreads();
        scan[t] += v;
        __syncthreads();
    }
    if (nq) kmap[scan[t] - 1] = t;
}

__global__ void expand_maps_k(const int* __restrict__ qidx, const int* __restrict__ kmap,
                              int* __restrict__ qmap, int* __restrict__ krmap)
{
    int i = blockIdx.x * 256 + threadIdx.x;
    if (i < 32*128) { int b = i >> 7; int t = i & 127; qmap[i] = b*1024 + qidx[t]; }
    if (i < 32*896) { int b = i / 896; int t = i - b*896; krmap[i] = b*1024 + kmap[t]; }
}

// ---------------------------------------------------------------------------
// mask dtype sniff + canonicalize to uint8[28672]
// ---------------------------------------------------------------------------
__global__ void mask_prep_k(const unsigned char* __restrict__ msrc,
                            unsigned char* __restrict__ mu8)
{
    __shared__ int f_u8, f_i32;
    int t = threadIdx.x;
    if (t == 0) { f_u8 = 0; f_i32 = 0; }
    __syncthreads();
    int lu8 = 0, li32 = 0;
    for (int i = t; i < 28672; i += 256) {
        unsigned char v = msrc[i];
        if (v) {
            if (i & 3) lu8 = 1;
            else if ((i & 7) == 4) li32 = 1;
        }
    }
    if (lu8) atomicOr(&f_u8, 1);
    if (li32) atomicOr(&f_i32, 1);
    __syncthreads();
    int mode = f_u8 ? 0 : (f_i32 ? 1 : 2);
    for (int i = t; i < 28672; i += 256) {
        unsigned char v;
        if (mode == 0)      v = msrc[i] ? 1 : 0;
        else if (mode == 1) v = ((const int*)msrc)[i] ? 1 : 0;
        else                v = ((const long long*)msrc)[i] ? 1 : 0;
        mu8[i] = v;
    }
}

// ---------------------------------------------------------------------------
// Fused attention: one block per (b,h). 256 threads = 4 waves.
// Thread t: q = t>>1 (0..127); half = t&1 (k-half for scores, d-half for PV).
// Online softmax over 14 tiles of 64 keys; K/V staged in LDS (coalesced);
// P tile in LDS with (k+q)&63 rotation (bank-conflict-free PV reads).
// Partner reduction (t^1) is intra-wave -> shuffle; P write->read is
// pair-within-wave -> no extra barrier needed.
// ---------------------------------------------------------------------------
__global__ __launch_bounds__(256) void attn_fused_k(
    const float* __restrict__ Q, const float* __restrict__ Kg, const float* __restrict__ Vg,
    const unsigned char* __restrict__ mask, float* __restrict__ out)
{
    __shared__ union SU {
        float Qs[128][36];
        float Ps[128][64];
    } U;
    __shared__ float Ks[64][36];
    __shared__ float Vs[64][36];
    const int t = threadIdx.x;
    const int bh = blockIdx.x;
    const int b = bh >> 3, h = bh & 7;

    // stage Q tile (coalesced float4)
    {
        int r0 = t >> 3;
        int c = (t & 7) * 4;
        #pragma unroll
        for (int it = 0; it < 4; ++it) {
            int r = r0 + 32 * it;
            *(float4*)&U.Qs[r][c] =
                *(const float4*)&Q[((size_t)(b*128 + r))*256 + h*32 + c];
        }
    }
    __syncthreads();
    const int q = t >> 1;
    const int half = t & 1;
    float qreg[32];
    #pragma unroll
    for (int d = 0; d < 32; ++d) qreg[d] = U.Qs[q][d];
    float m = -3.0e38f, l = 0.f;
    float O[16];
    #pragma unroll
    for (int i = 0; i < 16; ++i) O[i] = 0.f;
    const unsigned char* mrow = mask + b * 896;

    for (int kt = 0; kt < 14; ++kt) {
        __syncthreads();   // previous tile fully consumed (also orders Qs->Ps reuse)
        {
            int r0 = t >> 3;
            int c = (t & 7) * 4;
            #pragma unroll
            for (int it = 0; it < 2; ++it) {
                int r = r0 + 32 * it;
                size_t g = ((size_t)(b*896 + kt*64 + r))*256 + h*32 + c;
                *(float4*)&Ks[r][c] = *(const float4*)&Kg[g];
                *(float4*)&Vs[r][c] = *(const float4*)&Vg[g];
            }
        }
        __syncthreads();
        // ---- scores: 32 keys per thread ----
        float s[32];
        float tmax = -3.0e38f;
        #pragma unroll
        for (int j = 0; j < 32; ++j) {
            int k = half * 32 + j;
            float a0 = 0.f, a1 = 0.f, a2 = 0.f, a3 = 0.f;
            #pragma unroll
            for (int d0 = 0; d0 < 32; d0 += 4) {
                float4 kv = *(float4*)&Ks[k][d0];
                a0 += qreg[d0+0] * kv.x;
                a1 += qreg[d0+1] * kv.y;
                a2 += qreg[d0+2] * kv.z;
                a3 += qreg[d0+3] * kv.w;
            }
            float sc = ((a0+a1)+(a2+a3)) * 0.17677669529663687f; // 1/sqrt(32)
            sc = mrow[kt*64 + k] ? -1e9f : sc;
            s[j] = sc;
            tmax = fmaxf(tmax, sc);
        }
        tmax = fmaxf(tmax, __shfl_xor(tmax, 1));
        float mnew = fmaxf(m, tmax);
        float resc = __expf(m - mnew);
        float psum = 0.f;
        #pragma unroll
        for (int j = 0; j < 32; ++j) {
            float p = __expf(s[j] - mnew);
            s[j] = p;
            psum += p;
        }
        psum += __shfl_xor(psum, 1);
        l = l * resc + psum;
        m = mnew;
        #pragma unroll
        for (int i = 0; i < 16; ++i) O[i] *= resc;
        // publish P (rotated layout); partner lanes are in the same wave
        #pragma unroll
        for (int j = 0; j < 32; ++j) {
            int k = half * 32 + j;
            U.Ps[q][(k + q) & 63] = s[j];
        }
        // ---- PV: 16 output dims per thread ----
        #pragma unroll 16
        for (int k = 0; k < 64; ++k) {
            float p = U.Ps[q][(k + q) & 63];
            #pragma unroll
            for (int i = 0; i < 4; ++i) {
                float4 vv = *(float4*)&Vs[k][half*16 + 4*i];
                O[4*i+0] += p * vv.x;
                O[4*i+1] += p * vv.y;
                O[4*i+2] += p * vv.z;
                O[4*i+3] += p * vv.w;
            }
        }
    }
    float inv = 1.0f / l;
    #pragma unroll
    for (int i = 0; i < 16; ++i) O[i] *= inv;
    float* op = out + ((size_t)(b*128 + q))*256 + h*32 + half*16;
    #pragma unroll
    for (int i = 0; i < 4; ++i) {
        float4 v4; v4.x = O[4*i]; v4.y = O[4*i+1]; v4.z = O[4*i+2]; v4.w = O[4*i+3];
        *(float4*)&op[4*i] = v4;
    }
}

// ---------------------------------------------------------------------------
extern "C" void kernel_launch(void* const* d_in, const int* in_sizes, int n_in,
                              void* d_out, int out_size, void* d_ws, size_t ws_size,
                              hipStream_t stream)
{
    const float* node       = (const float*)d_in[0];
    const int*   cate       = (const int*)d_in[1];
    const float* cont       = (const float*)d_in[2];
    const int*   qidx       = (const int*)d_in[3];
    const unsigned char* mask = (const unsigned char*)d_in[4];
    const float* cate_table = (const float*)d_in[5];
    const float* pos_emb    = (const float*)d_in[6];
    const float* node_W     = (const float*)d_in[7];
    const float* node_b     = (const float*)d_in[8];
    const float* node_ln_g  = (const float*)d_in[9];
    const float* node_ln_b  = (const float*)d_in[10];
    const float* cate_W     = (const float*)d_in[11];
    const float* cate_b     = (const float*)d_in[12];
    const float* cate_ln_g  = (const float*)d_in[13];
    const float* cate_ln_b  = (const float*)d_in[14];
    const float* bn_g       = (const float*)d_in[15];
    const float* bn_b       = (const float*)d_in[16];
    const float* cont_W     = (const float*)d_in[17];
    const float* cont_b     = (const float*)d_in[18];
    const float* cont_ln_g  = (const float*)d_in[19];
    const float* cont_ln_b  = (const float*)d_in[20];
    const float* comb_W     = (const float*)d_in[21];
    const float* comb_b     = (const float*)d_in[22];
    const float* comb_ln_g  = (const float*)d_in[23];
    const float* comb_ln_b  = (const float*)d_in[24];
    const float* q_W        = (const float*)d_in[25];
    const float* q_b        = (const float*)d_in[26];
    const float* k_W        = (const float*)d_in[27];
    const float* k_b        = (const float*)d_in[28];
    const float* v_W        = (const float*)d_in[29];
    const float* v_b        = (const float*)d_in[30];
    const float* reg_W1     = (const float*)d_in[31];
    const float* reg_b1     = (const float*)d_in[32];
    const float* reg_ln_g   = (const float*)d_in[33];
    const float* reg_ln_b   = (const float*)d_in[34];
    const float* reg_W2     = (const float*)d_in[35];
    const float* reg_b2     = (const float*)d_in[36];

    char* ws = (char*)d_ws;
    float* seq3 = (float*)(ws + 0);            // 32768*768*4
    float* tmp  = (float*)(ws + 100663296);    // 32768*256*4
    float* seq  = (float*)(ws + 134217728);    // 32768*256*4
    // seq3 region recycled after comb GEMM:
    float* Qb   = (float*)(ws + 0);
    float* Kb   = (float*)(ws + 4194304);
    float* Vb   = (float*)(ws + 33554432);
    float* AO   = (float*)(ws + 62914560);
    float* Hb   = (float*)(ws + 67108864);
    float* stats= (float*)(ws + 167772160);
    int*   kmap = (int*)  (ws + 167772224);
    int*   qmap = (int*)  (ws + 167775808);
    int*   krmap= (int*)  (ws + 167792192);
    unsigned char* mu8 = (unsigned char*)(ws + 167907328);
    float* outp = (float*)d_out;

    hipMemsetAsync(stats, 0, 64, stream);
    bn_stats_k<<<256, 256, 0, stream>>>(cont, stats);
    mask_prep_k<<<1, 256, 0, stream>>>(mask, mu8);

    // node path
    gemm_k<0><<<dim3(512,4), 256, 0, stream>>>(32768,256,1024, node, nullptr, nullptr, node_W, node_b, tmp);
    ln_k<<<8192,256,0,stream>>>(32768, tmp, node_ln_g, node_ln_b, seq3, 768, 0, 1, nullptr);
    // cate path
    gemm_k<1><<<dim3(512,4), 256, 0, stream>>>(32768,256,1024, nullptr, cate, cate_table, cate_W, cate_b, tmp);
    ln_k<<<8192,256,0,stream>>>(32768, tmp, cate_ln_g, cate_ln_b, seq3, 768, 256, 1, nullptr);
    // cont path
    cont_k<<<2048,256,0,stream>>>(cont, stats, bn_g, bn_b, cont_W, cont_b, cont_ln_g, cont_ln_b, seq3);
    // comb
    gemm_k<0><<<dim3(512,4),256,0,stream>>>(32768,256,768, seq3, nullptr, nullptr, comb_W, comb_b, tmp);
    ln_k<<<8192,256,0,stream>>>(32768, tmp, comb_ln_g, comb_ln_b, seq, 256, 0, 0, pos_emb);
    // index maps
    build_maps_k<<<1,1024,0,stream>>>(qidx, kmap);
    expand_maps_k<<<112,256,0,stream>>>(qidx, kmap, qmap, krmap);
    // Q/K/V projections
    gemm_k<2><<<dim3(64,4),256,0,stream>>>(4096,256,256, seq, qmap, nullptr, q_W, q_b, Qb);
    gemm_k<2><<<dim3(448,4),256,0,stream>>>(28672,256,256, seq, krmap, nullptr, k_W, k_b, Kb);
    gemm_k<2><<<dim3(448,4),256,0,stream>>>(28672,256,256, seq, krmap, nullptr, v_W, v_b, Vb);
    // attention (fused, LDS-staged)
    attn_fused_k<<<256,256,0,stream>>>(Qb, Kb, Vb, mu8, AO);
    // regression head
    gemm_k<0><<<dim3(64,4),256,0,stream>>>(4096,256,256, AO, nullptr, nullptr, reg_W1, reg_b1, tmp);
    ln_k<<<1024,256,0,stream>>>(4096, tmp, reg_ln_g, reg_ln_b, Hb, 256, 0, 1, nullptr);
    gemm_k<0><<<dim3(64,4),256,0,stream>>>(4096,256,256, Hb, nullptr, nullptr, reg_W2, reg_b2, outp);
}

// Round 4
// 655.645 us; speedup vs baseline: 2.7770x; 1.9060x over previous
//
#include <hip/hip_runtime.h>
#include <cstdint>

#define EPSV 1e-5f

typedef __attribute__((ext_vector_type(8))) short short8v;   // 8 bf16
typedef __attribute__((ext_vector_type(4))) float float4v;

__device__ inline unsigned short f2bf(float f) {
    union { float f; unsigned int u; } v; v.f = f;
    unsigned int r = v.u + 0x7FFF + ((v.u >> 16) & 1);
    return (unsigned short)(r >> 16);
}

// ---------------------------------------------------------------------------
// Weight transpose+convert: Wt[n][k] = bf16(W[k][n]); N = 256 fixed.
// ---------------------------------------------------------------------------
__global__ __launch_bounds__(256) void wt_k(const float* __restrict__ W,
                                            unsigned short* __restrict__ Wt, int K)
{
    int id = blockIdx.x * 256 + threadIdx.x;   // id = n*K + k
    if (id >= K * 256) return;
    int n = id / K, k = id - n * K;
    Wt[id] = f2bf(W[(size_t)k * 256 + n]);
}

// ---------------------------------------------------------------------------
// MFMA bf16 GEMM: C[M,256] = A[M,K] @ B[K,256] + bias, fp32 out.
// Block: 256 thr (4 waves). Tile: 64(M) x 256(N full). Wave w -> cols w*64..+63.
// Bt: bf16 [256][K] (pre-transposed weights).
// MODE 0: A direct. MODE 1: cate-table gather (fp32 only). MODE 2: row gather.
// SRCBF: A source is bf16 (ushort) instead of fp32.
// ---------------------------------------------------------------------------
template<int MODE, int SRCBF>
__global__ __launch_bounds__(256) void gemm_mfma_k(
    int M, int K,
    const void* __restrict__ Asrc,
    const int* __restrict__ gidx,
    const float* __restrict__ table,
    const unsigned short* __restrict__ Bt,
    const float* __restrict__ bias,
    float* __restrict__ C)
{
    __shared__ unsigned short As[64][40];    // pad: 40 bf16 = 80 B (16B-aligned rows)
    __shared__ unsigned short Bs[256][40];
    const int t = threadIdx.x;
    const int bm = blockIdx.x * 64;
    const int w = t >> 6;          // wave -> n-block
    const int l = t & 63;
    const int lr = l & 15;         // frag row/col
    const int lg = l >> 4;         // k-group

    float4v acc[4][4];
    #pragma unroll
    for (int i = 0; i < 4; ++i)
        #pragma unroll
        for (int j = 0; j < 4; ++j) acc[i][j] = (float4v)0.f;

    const int arow = t >> 2;         // 0..63
    const int ac8  = (t & 3) * 8;    // 0,8,16,24

    for (int kt = 0; kt < K; kt += 32) {
        // ---- issue global loads (before barrier: overlap w/ prev compute) ----
        short8v av;
        if (SRCBF) {
            const unsigned short* ap;
            if (MODE == 2) ap = (const unsigned short*)Asrc + (size_t)gidx[bm + arow] * K + kt + ac8;
            else           ap = (const unsigned short*)Asrc + (size_t)(bm + arow) * K + kt + ac8;
            av = *(const short8v*)ap;
        } else {
            const float* ap;
            if (MODE == 1) {
                int gk = kt + ac8;
                int idx = gidx[(bm + arow) * 4 + (gk >> 8)];
                ap = table + (size_t)idx * 256 + (gk & 255);
            } else if (MODE == 2) {
                ap = (const float*)Asrc + (size_t)gidx[bm + arow] * K + kt + ac8;
            } else {
                ap = (const float*)Asrc + (size_t)(bm + arow) * K + kt + ac8;
            }
            float4 f0 = *(const float4*)ap;
            float4 f1 = *(const float4*)(ap + 4);
            av[0] = (short)f2bf(f0.x); av[1] = (short)f2bf(f0.y);
            av[2] = (short)f2bf(f0.z); av[3] = (short)f2bf(f0.w);
            av[4] = (short)f2bf(f1.x); av[5] = (short)f2bf(f1.y);
            av[6] = (short)f2bf(f1.z); av[7] = (short)f2bf(f1.w);
        }
        const unsigned short* bsrc = Bt + (size_t)t * K + kt;
        short8v b0 = *(const short8v*)(bsrc);
        short8v b1 = *(const short8v*)(bsrc + 8);
        short8v b2 = *(const short8v*)(bsrc + 16);
        short8v b3 = *(const short8v*)(bsrc + 24);

        __syncthreads();   // previous tile fully consumed
        *(short8v*)&As[arow][ac8] = av;
        *(short8v*)&Bs[t][0]  = b0;
        *(short8v*)&Bs[t][8]  = b1;
        *(short8v*)&Bs[t][16] = b2;
        *(short8v*)&Bs[t][24] = b3;
        __syncthreads();

        short8v af[4], bf[4];
        #pragma unroll
        for (int i = 0; i < 4; ++i) af[i] = *(const short8v*)&As[i*16 + lr][lg*8];
        #pragma unroll
        for (int j = 0; j < 4; ++j) bf[j] = *(const short8v*)&Bs[w*64 + j*16 + lr][lg*8];
        #pragma unroll
        for (int i = 0; i < 4; ++i)
            #pragma unroll
            for (int j = 0; j < 4; ++j)
                acc[i][j] = __builtin_amdgcn_mfma_f32_16x16x32_bf16(af[i], bf[j], acc[i][j], 0, 0, 0);
    }

    // epilogue: D col = lane&15, row = (lane>>4)*4 + reg
    #pragma unroll
    for (int i = 0; i < 4; ++i) {
        #pragma unroll
        for (int j = 0; j < 4; ++j) {
            int c = w*64 + j*16 + lr;
            float bv = bias[c];
            #pragma unroll
            for (int r4 = 0; r4 < 4; ++r4) {
                int r = bm + i*16 + lg*4 + r4;
                C[(size_t)r * 256 + c] = acc[i][j][r4] + bv;
            }
        }
    }
}

// ---------------------------------------------------------------------------
// LayerNorm over H=256 (fp32 in), bf16 out. Optional +pos_emb and leaky.
// ---------------------------------------------------------------------------
__global__ __launch_bounds__(256) void ln_k(
    int M, const float* __restrict__ X,
    const float* __restrict__ g, const float* __restrict__ b,
    unsigned short* __restrict__ Y, int ldY, int colOff,
    int do_leaky, const float* __restrict__ pos)
{
    int wid = (blockIdx.x * 256 + threadIdx.x) >> 6;
    int lane = threadIdx.x & 63;
    if (wid >= M) return;
    const float* x = X + (size_t)wid * 256;
    float v[4]; float s = 0.f;
    #pragma unroll
    for (int j = 0; j < 4; ++j) { v[j] = x[lane + 64*j]; s += v[j]; }
    #pragma unroll
    for (int o = 32; o; o >>= 1) s += __shfl_xor(s, o);
    float mu = s * (1.0f/256.0f);
    float q = 0.f;
    #pragma unroll
    for (int j = 0; j < 4; ++j) { float d = v[j]-mu; q += d*d; }
    #pragma unroll
    for (int o = 32; o; o >>= 1) q += __shfl_xor(q, o);
    float rstd = rsqrtf(q*(1.0f/256.0f) + EPSV);
    #pragma unroll
    for (int j = 0; j < 4; ++j) {
        int c = lane + 64*j;
        float y = (v[j]-mu)*rstd*g[c] + b[c];
        if (pos) y += pos[(size_t)(wid & 1023) * 256 + c];
        if (do_leaky) y = (y >= 0.f) ? y : 0.01f*y;
        Y[(size_t)wid * ldY + colOff + c] = f2bf(y);
    }
}

// ---------------------------------------------------------------------------
// BatchNorm statistics: stats[0..7]=sum, [8..15]=sumsq
// ---------------------------------------------------------------------------
__global__ __launch_bounds__(256) void bn_stats_k(const float* __restrict__ cont,
                                                  float* __restrict__ stats)
{
    __shared__ float ss[8], sq[8];
    int tid = threadIdx.x;
    if (tid < 8) { ss[tid] = 0.f; sq[tid] = 0.f; }
    __syncthreads();
    int gt = blockIdx.x * 256 + tid;
    float s = 0.f, q = 0.f;
    for (int e = gt; e < 32768*8; e += 256*256) { float v = cont[e]; s += v; q += v*v; }
    int f = gt & 7;
    atomicAdd(&ss[f], s);
    atomicAdd(&sq[f], q);
    __syncthreads();
    if (tid < 8) { atomicAdd(&stats[tid], ss[tid]); atomicAdd(&stats[8+tid], sq[tid]); }
}

// ---------------------------------------------------------------------------
// cont path fused: BN-normalize + (8x256 GEMM) + bias + LN + leaky -> bf16
// ---------------------------------------------------------------------------
__global__ __launch_bounds__(256) void cont_k(
    const float* __restrict__ cont, const float* __restrict__ stats,
    const float* __restrict__ bn_g, const float* __restrict__ bn_b,
    const float* __restrict__ W, const float* __restrict__ bias,
    const float* __restrict__ g, const float* __restrict__ bL,
    unsigned short* __restrict__ seq3)
{
    __shared__ float Ws[8][256];
    __shared__ float sscale[8], sshift[8];
    __shared__ float cr[8];
    __shared__ float red[8];
    int tid = threadIdx.x;
    #pragma unroll
    for (int d = 0; d < 8; ++d) Ws[d][tid] = W[d*256 + tid];
    if (tid < 8) {
        float mean = stats[tid] * (1.0f/32768.0f);
        float var  = stats[8+tid] * (1.0f/32768.0f) - mean*mean;
        float r = rsqrtf(var + EPSV);
        float sc = r * bn_g[tid];
        sscale[tid] = sc;
        sshift[tid] = bn_b[tid] - mean*sc;
    }
    __syncthreads();
    int lane = tid & 63, wv = tid >> 6;
    float gv = g[tid], bv = bL[tid], biasv = bias[tid];
    for (int row = blockIdx.x; row < 32768; row += gridDim.x) {
        if (tid < 8) cr[tid] = cont[(size_t)row*8 + tid]*sscale[tid] + sshift[tid];
        __syncthreads();
        float acc = biasv;
        #pragma unroll
        for (int d = 0; d < 8; ++d) acc += cr[d]*Ws[d][tid];
        float s = acc;
        #pragma unroll
        for (int o = 32; o; o >>= 1) s += __shfl_xor(s, o);
        if (lane == 0) red[wv] = s;
        __syncthreads();
        float mu = (red[0]+red[1]+red[2]+red[3]) * (1.0f/256.0f);
        float dc = acc - mu;
        float qv = dc*dc;
        #pragma unroll
        for (int o = 32; o; o >>= 1) qv += __shfl_xor(qv, o);
        if (lane == 0) red[4+wv] = qv;
        __syncthreads();
        float var = (red[4]+red[5]+red[6]+red[7]) * (1.0f/256.0f);
        float y = dc * rsqrtf(var + EPSV) * gv + bv;
        y = (y >= 0.f) ? y : 0.01f*y;
        seq3[(size_t)row*768 + 512 + tid] = f2bf(y);
        __syncthreads();
    }
}

// ---------------------------------------------------------------------------
// key-index construction
// ---------------------------------------------------------------------------
__global__ void build_maps_k(const int* __restrict__ qidx, int* __restrict__ kmap)
{
    __shared__ int flag[1024];
    __shared__ int scan[1024];
    int t = threadIdx.x;
    flag[t] = 0;
    __syncthreads();
    if (t < 128) flag[qidx[t]] = 1;
    __syncthreads();
    int nq = 1 - flag[t];
    scan[t] = nq;
    __syncthreads();
    for (int off = 1; off < 1024; off <<= 1) {
        int v = (t >= off) ? scan[t - off] : 0;
        __syncthreads();
        scan[t] += v;
        __syncthreads();
    }
    if (nq) kmap[scan[t] - 1] = t;
}

__global__ void expand_maps_k(const int* __restrict__ qidx, const int* __restrict__ kmap,
                              int* __restrict__ qmap, int* __restrict__ krmap)
{
    int i = blockIdx.x * 256 + threadIdx.x;
    if (i < 32*128) { int b = i >> 7; int t = i & 127; qmap[i] = b*1024 + qidx[t]; }
    if (i < 32*896) { int b = i / 896; int t = i - b*896; krmap[i] = b*1024 + kmap[t]; }
}

// ---------------------------------------------------------------------------
// mask dtype sniff + canonicalize to uint8[28672]
// ---------------------------------------------------------------------------
__global__ void mask_prep_k(const unsigned char* __restrict__ msrc,
                            unsigned char* __restrict__ mu8)
{
    __shared__ int f_u8, f_i32;
    int t = threadIdx.x;
    if (t == 0) { f_u8 = 0; f_i32 = 0; }
    __syncthreads();
    int lu8 = 0, li32 = 0;
    for (int i = t; i < 28672; i += 256) {
        unsigned char v = msrc[i];
        if (v) {
            if (i & 3) lu8 = 1;
            else if ((i & 7) == 4) li32 = 1;
        }
    }
    if (lu8) atomicOr(&f_u8, 1);
    if (li32) atomicOr(&f_i32, 1);
    __syncthreads();
    int mode = f_u8 ? 0 : (f_i32 ? 1 : 2);
    for (int i = t; i < 28672; i += 256) {
        unsigned char v;
        if (mode == 0)      v = msrc[i] ? 1 : 0;
        else if (mode == 1) v = ((const int*)msrc)[i] ? 1 : 0;
        else                v = ((const long long*)msrc)[i] ? 1 : 0;
        mu8[i] = v;
    }
}

// ---------------------------------------------------------------------------
// Fused attention: one block per (b,h); fp32 in, bf16 out.
// ---------------------------------------------------------------------------
__global__ __launch_bounds__(256) void attn_fused_k(
    const float* __restrict__ Q, const float* __restrict__ Kg, const float* __restrict__ Vg,
    const unsigned char* __restrict__ mask, unsigned short* __restrict__ out)
{
    __shared__ union SU {
        float Qs[128][36];
        float Ps[128][64];
    } U;
    __shared__ float Ks[64][36];
    __shared__ float Vs[64][36];
    const int t = threadIdx.x;
    const int bh = blockIdx.x;
    const int b = bh >> 3, h = bh & 7;

    {
        int r0 = t >> 3;
        int c = (t & 7) * 4;
        #pragma unroll
        for (int it = 0; it < 4; ++it) {
            int r = r0 + 32 * it;
            *(float4*)&U.Qs[r][c] =
                *(const float4*)&Q[((size_t)(b*128 + r))*256 + h*32 + c];
        }
    }
    __syncthreads();
    const int q = t >> 1;
    const int half = t & 1;
    float qreg[32];
    #pragma unroll
    for (int d = 0; d < 32; ++d) qreg[d] = U.Qs[q][d];
    float m = -3.0e38f, l = 0.f;
    float O[16];
    #pragma unroll
    for (int i = 0; i < 16; ++i) O[i] = 0.f;
    const unsigned char* mrow = mask + b * 896;

    for (int kt = 0; kt < 14; ++kt) {
        __syncthreads();
        {
            int r0 = t >> 3;
            int c = (t & 7) * 4;
            #pragma unroll
            for (int it = 0; it < 2; ++it) {
                int r = r0 + 32 * it;
                size_t gg = ((size_t)(b*896 + kt*64 + r))*256 + h*32 + c;
                *(float4*)&Ks[r][c] = *(const float4*)&Kg[gg];
                *(float4*)&Vs[r][c] = *(const float4*)&Vg[gg];
            }
        }
        __syncthreads();
        float s[32];
        float tmax = -3.0e38f;
        #pragma unroll
        for (int j = 0; j < 32; ++j) {
            int k = half * 32 + j;
            float a0 = 0.f, a1 = 0.f, a2 = 0.f, a3 = 0.f;
            #pragma unroll
            for (int d0 = 0; d0 < 32; d0 += 4) {
                float4 kv = *(float4*)&Ks[k][d0];
                a0 += qreg[d0+0] * kv.x;
                a1 += qreg[d0+1] * kv.y;
                a2 += qreg[d0+2] * kv.z;
                a3 += qreg[d0+3] * kv.w;
            }
            float sc = ((a0+a1)+(a2+a3)) * 0.17677669529663687f;
            sc = mrow[kt*64 + k] ? -1e9f : sc;
            s[j] = sc;
            tmax = fmaxf(tmax, sc);
        }
        tmax = fmaxf(tmax, __shfl_xor(tmax, 1));
        float mnew = fmaxf(m, tmax);
        float resc = __expf(m - mnew);
        float psum = 0.f;
        #pragma unroll
        for (int j = 0; j < 32; ++j) {
            float p = __expf(s[j] - mnew);
            s[j] = p;
            psum += p;
        }
        psum += __shfl_xor(psum, 1);
        l = l * resc + psum;
        m = mnew;
        #pragma unroll
        for (int i = 0; i < 16; ++i) O[i] *= resc;
        #pragma unroll
        for (int j = 0; j < 32; ++j) {
            int k = half * 32 + j;
            U.Ps[q][(k + q) & 63] = s[j];
        }
        #pragma unroll 16
        for (int k = 0; k < 64; ++k) {
            float p = U.Ps[q][(k + q) & 63];
            #pragma unroll
            for (int i = 0; i < 4; ++i) {
                float4 vv = *(float4*)&Vs[k][half*16 + 4*i];
                O[4*i+0] += p * vv.x;
                O[4*i+1] += p * vv.y;
                O[4*i+2] += p * vv.z;
                O[4*i+3] += p * vv.w;
            }
        }
    }
    float inv = 1.0f / l;
    #pragma unroll
    for (int i = 0; i < 16; ++i) O[i] *= inv;
    unsigned short* op = out + ((size_t)(b*128 + q))*256 + h*32 + half*16;
    short8v o0, o1;
    #pragma unroll
    for (int i = 0; i < 8; ++i) { o0[i] = (short)f2bf(O[i]); o1[i] = (short)f2bf(O[8+i]); }
    *(short8v*)&op[0] = o0;
    *(short8v*)&op[8] = o1;
}

// ---------------------------------------------------------------------------
extern "C" void kernel_launch(void* const* d_in, const int* in_sizes, int n_in,
                              void* d_out, int out_size, void* d_ws, size_t ws_size,
                              hipStream_t stream)
{
    const float* node       = (const float*)d_in[0];
    const int*   cate       = (const int*)d_in[1];
    const float* cont       = (const float*)d_in[2];
    const int*   qidx       = (const int*)d_in[3];
    const unsigned char* mask = (const unsigned char*)d_in[4];
    const float* cate_table = (const float*)d_in[5];
    const float* pos_emb    = (const float*)d_in[6];
    const float* node_W     = (const float*)d_in[7];
    const float* node_b     = (const float*)d_in[8];
    const float* node_ln_g  = (const float*)d_in[9];
    const float* node_ln_b  = (const float*)d_in[10];
    const float* cate_W     = (const float*)d_in[11];
    const float* cate_b     = (const float*)d_in[12];
    const float* cate_ln_g  = (const float*)d_in[13];
    const float* cate_ln_b  = (const float*)d_in[14];
    const float* bn_g       = (const float*)d_in[15];
    const float* bn_b       = (const float*)d_in[16];
    const float* cont_W     = (const float*)d_in[17];
    const float* cont_b     = (const float*)d_in[18];
    const float* cont_ln_g  = (const float*)d_in[19];
    const float* cont_ln_b  = (const float*)d_in[20];
    const float* comb_W     = (const float*)d_in[21];
    const float* comb_b     = (const float*)d_in[22];
    const float* comb_ln_g  = (const float*)d_in[23];
    const float* comb_ln_b  = (const float*)d_in[24];
    const float* q_W        = (const float*)d_in[25];
    const float* q_b        = (const float*)d_in[26];
    const float* k_W        = (const float*)d_in[27];
    const float* k_b        = (const float*)d_in[28];
    const float* v_W        = (const float*)d_in[29];
    const float* v_b        = (const float*)d_in[30];
    const float* reg_W1     = (const float*)d_in[31];
    const float* reg_b1     = (const float*)d_in[32];
    const float* reg_ln_g   = (const float*)d_in[33];
    const float* reg_ln_b   = (const float*)d_in[34];
    const float* reg_W2     = (const float*)d_in[35];
    const float* reg_b2     = (const float*)d_in[36];

    char* ws = (char*)d_ws;
    unsigned short* seq3bf = (unsigned short*)(ws + 0);          // 32768*768*2 = 50331648
    float*          tmp    = (float*)(ws + 50331648);            // 32768*256*4 = 33554432
    unsigned short* seqbf  = (unsigned short*)(ws + 83886080);   // 32768*256*2 = 16777216
    float*          Qb     = (float*)(ws + 100663296);           // 4096*256*4
    float*          Kb     = (float*)(ws + 104857600);           // 28672*256*4
    float*          Vb     = (float*)(ws + 134217728);           // 28672*256*4
    unsigned short* AObf   = (unsigned short*)(ws + 163577856);  // 4096*256*2
    unsigned short* Hbf    = (unsigned short*)(ws + 0);          // reuse seq3bf region
    float* stats = (float*)(ws + 165675008);
    int*   kmap  = (int*)  (ws + 165675072);
    int*   qmap  = (int*)  (ws + 165678656);
    int*   krmap = (int*)  (ws + 165695040);
    unsigned char* mu8 = (unsigned char*)(ws + 165809728);
    unsigned short* node_Wt = (unsigned short*)(ws + 165838400);
    unsigned short* cate_Wt = (unsigned short*)(ws + 166362688);
    unsigned short* comb_Wt = (unsigned short*)(ws + 166886976);
    unsigned short* q_Wt    = (unsigned short*)(ws + 167280192);
    unsigned short* k_Wt    = (unsigned short*)(ws + 167411264);
    unsigned short* v_Wt    = (unsigned short*)(ws + 167542336);
    unsigned short* r1_Wt   = (unsigned short*)(ws + 167673408);
    unsigned short* r2_Wt   = (unsigned short*)(ws + 167804480);
    float* outp = (float*)d_out;

    hipMemsetAsync(stats, 0, 64, stream);
    bn_stats_k<<<256, 256, 0, stream>>>(cont, stats);
    mask_prep_k<<<1, 256, 0, stream>>>(mask, mu8);
    // weight transpose+convert
    wt_k<<<1024, 256, 0, stream>>>(node_W, node_Wt, 1024);
    wt_k<<<1024, 256, 0, stream>>>(cate_W, cate_Wt, 1024);
    wt_k<<<768,  256, 0, stream>>>(comb_W, comb_Wt, 768);
    wt_k<<<256,  256, 0, stream>>>(q_W,  q_Wt,  256);
    wt_k<<<256,  256, 0, stream>>>(k_W,  k_Wt,  256);
    wt_k<<<256,  256, 0, stream>>>(v_W,  v_Wt,  256);
    wt_k<<<256,  256, 0, stream>>>(reg_W1, r1_Wt, 256);
    wt_k<<<256,  256, 0, stream>>>(reg_W2, r2_Wt, 256);

    // node path
    gemm_mfma_k<0,0><<<512, 256, 0, stream>>>(32768, 1024, node, nullptr, nullptr, node_Wt, node_b, tmp);
    ln_k<<<8192,256,0,stream>>>(32768, tmp, node_ln_g, node_ln_b, seq3bf, 768, 0, 1, nullptr);
    // cate path
    gemm_mfma_k<1,0><<<512, 256, 0, stream>>>(32768, 1024, nullptr, cate, cate_table, cate_Wt, cate_b, tmp);
    ln_k<<<8192,256,0,stream>>>(32768, tmp, cate_ln_g, cate_ln_b, seq3bf, 768, 256, 1, nullptr);
    // cont path
    cont_k<<<2048,256,0,stream>>>(cont, stats, bn_g, bn_b, cont_W, cont_b, cont_ln_g, cont_ln_b, seq3bf);
    // comb
    gemm_mfma_k<0,1><<<512, 256, 0, stream>>>(32768, 768, seq3bf, nullptr, nullptr, comb_Wt, comb_b, tmp);
    ln_k<<<8192,256,0,stream>>>(32768, tmp, comb_ln_g, comb_ln_b, seqbf, 256, 0, 0, pos_emb);
    // index maps
    build_maps_k<<<1,1024,0,stream>>>(qidx, kmap);
    expand_maps_k<<<112,256,0,stream>>>(qidx, kmap, qmap, krmap);
    // Q/K/V projections (row gather from bf16 seq)
    gemm_mfma_k<2,1><<<64,  256, 0, stream>>>(4096,  256, seqbf, qmap,  nullptr, q_Wt, q_b, Qb);
    gemm_mfma_k<2,1><<<448, 256, 0, stream>>>(28672, 256, seqbf, krmap, nullptr, k_Wt, k_b, Kb);
    gemm_mfma_k<2,1><<<448, 256, 0, stream>>>(28672, 256, seqbf, krmap, nullptr, v_Wt, v_b, Vb);
    // attention
    attn_fused_k<<<256,256,0,stream>>>(Qb, Kb, Vb, mu8, AObf);
    // regression head
    gemm_mfma_k<0,1><<<64, 256, 0, stream>>>(4096, 256, AObf, nullptr, nullptr, r1_Wt, reg_b1, tmp);
    ln_k<<<1024,256,0,stream>>>(4096, tmp, reg_ln_g, reg_ln_b, Hbf, 256, 0, 1, nullptr);
    gemm_mfma_k<0,1><<<64, 256, 0, stream>>>(4096, 256, Hbf, nullptr, nullptr, r2_Wt, reg_b2, outp);
}

// Round 5
// 483.198 us; speedup vs baseline: 3.7680x; 1.3569x over previous
//
#include <hip/hip_runtime.h>
#include <cstdint>

#define EPSV 1e-5f

typedef __attribute__((ext_vector_type(8))) short short8v;   // 8 bf16
typedef __attribute__((ext_vector_type(4))) float float4v;

__device__ inline unsigned short f2bf(float f) {
    union { float f; unsigned int u; } v; v.f = f;
    unsigned int r = v.u + 0x7FFF + ((v.u >> 16) & 1);
    return (unsigned short)(r >> 16);
}

// ---------------------------------------------------------------------------
// Weight transpose+convert: Wt[n][k] = bf16(W[k][n]); N = 256 fixed.
// ---------------------------------------------------------------------------
__global__ __launch_bounds__(256) void wt_k(const float* __restrict__ W,
                                            unsigned short* __restrict__ Wt, int K)
{
    int id = blockIdx.x * 256 + threadIdx.x;   // id = n*K + k
    if (id >= K * 256) return;
    int n = id / K, k = id - n * K;
    Wt[id] = f2bf(W[(size_t)k * 256 + n]);
}

// ---------------------------------------------------------------------------
// MFMA bf16 GEMM: C[M,256] = A[M,K] @ B[K,256] + bias.
// MODE 0: A direct. MODE 1: cate-table gather (fp32). MODE 2: row gather.
// SRCBF: A is bf16. OUTM: 0 = f32 [M][256]; 1 = bf16 [M][256];
//        2 = bf16 transposed V layout Vt[(bm/896)*256 + c][896] at col bm%896+row
// ---------------------------------------------------------------------------
template<int MODE, int SRCBF, int OUTM>
__global__ __launch_bounds__(256) void gemm_mfma_k(
    int M, int K,
    const void* __restrict__ Asrc,
    const int* __restrict__ gidx,
    const float* __restrict__ table,
    const unsigned short* __restrict__ Bt,
    const float* __restrict__ bias,
    void* __restrict__ Cout)
{
    __shared__ unsigned short As[64][40];
    __shared__ unsigned short Bs[256][40];
    const int t = threadIdx.x;
    const int bm = blockIdx.x * 64;
    const int w = t >> 6;
    const int l = t & 63;
    const int lr = l & 15;
    const int lg = l >> 4;

    float4v acc[4][4];
    #pragma unroll
    for (int i = 0; i < 4; ++i)
        #pragma unroll
        for (int j = 0; j < 4; ++j) acc[i][j] = (float4v)0.f;

    const int arow = t >> 2;
    const int ac8  = (t & 3) * 8;

    for (int kt = 0; kt < K; kt += 32) {
        short8v av;
        if (SRCBF) {
            const unsigned short* ap;
            if (MODE == 2) ap = (const unsigned short*)Asrc + (size_t)gidx[bm + arow] * K + kt + ac8;
            else           ap = (const unsigned short*)Asrc + (size_t)(bm + arow) * K + kt + ac8;
            av = *(const short8v*)ap;
        } else {
            const float* ap;
            if (MODE == 1) {
                int gk = kt + ac8;
                int idx = gidx[(bm + arow) * 4 + (gk >> 8)];
                ap = table + (size_t)idx * 256 + (gk & 255);
            } else if (MODE == 2) {
                ap = (const float*)Asrc + (size_t)gidx[bm + arow] * K + kt + ac8;
            } else {
                ap = (const float*)Asrc + (size_t)(bm + arow) * K + kt + ac8;
            }
            float4 f0 = *(const float4*)ap;
            float4 f1 = *(const float4*)(ap + 4);
            av[0] = (short)f2bf(f0.x); av[1] = (short)f2bf(f0.y);
            av[2] = (short)f2bf(f0.z); av[3] = (short)f2bf(f0.w);
            av[4] = (short)f2bf(f1.x); av[5] = (short)f2bf(f1.y);
            av[6] = (short)f2bf(f1.z); av[7] = (short)f2bf(f1.w);
        }
        const unsigned short* bsrc = Bt + (size_t)t * K + kt;
        short8v b0 = *(const short8v*)(bsrc);
        short8v b1 = *(const short8v*)(bsrc + 8);
        short8v b2 = *(const short8v*)(bsrc + 16);
        short8v b3 = *(const short8v*)(bsrc + 24);

        __syncthreads();
        *(short8v*)&As[arow][ac8] = av;
        *(short8v*)&Bs[t][0]  = b0;
        *(short8v*)&Bs[t][8]  = b1;
        *(short8v*)&Bs[t][16] = b2;
        *(short8v*)&Bs[t][24] = b3;
        __syncthreads();

        short8v af[4], bf[4];
        #pragma unroll
        for (int i = 0; i < 4; ++i) af[i] = *(const short8v*)&As[i*16 + lr][lg*8];
        #pragma unroll
        for (int j = 0; j < 4; ++j) bf[j] = *(const short8v*)&Bs[w*64 + j*16 + lr][lg*8];
        #pragma unroll
        for (int i = 0; i < 4; ++i)
            #pragma unroll
            for (int j = 0; j < 4; ++j)
                acc[i][j] = __builtin_amdgcn_mfma_f32_16x16x32_bf16(af[i], bf[j], acc[i][j], 0, 0, 0);
    }

    // epilogue: D col = lane&15, row = (lane>>4)*4 + reg
    #pragma unroll
    for (int i = 0; i < 4; ++i) {
        #pragma unroll
        for (int j = 0; j < 4; ++j) {
            int c = w*64 + j*16 + lr;
            float bv = bias[c];
            #pragma unroll
            for (int r4 = 0; r4 < 4; ++r4) {
                int rl = i*16 + lg*4 + r4;
                float val = acc[i][j][r4] + bv;
                if (OUTM == 0) {
                    ((float*)Cout)[(size_t)(bm + rl) * 256 + c] = val;
                } else if (OUTM == 1) {
                    ((unsigned short*)Cout)[(size_t)(bm + rl) * 256 + c] = f2bf(val);
                } else {
                    int vb = bm / 896;
                    int kl = bm - vb * 896 + rl;
                    ((unsigned short*)Cout)[((size_t)vb * 256 + c) * 896 + kl] = f2bf(val);
                }
            }
        }
    }
}

// ---------------------------------------------------------------------------
// LayerNorm over H=256 (fp32 in), bf16 out. Optional +pos_emb and leaky.
// ---------------------------------------------------------------------------
__global__ __launch_bounds__(256) void ln_k(
    int M, const float* __restrict__ X,
    const float* __restrict__ g, const float* __restrict__ b,
    unsigned short* __restrict__ Y, int ldY, int colOff,
    int do_leaky, const float* __restrict__ pos)
{
    int wid = (blockIdx.x * 256 + threadIdx.x) >> 6;
    int lane = threadIdx.x & 63;
    if (wid >= M) return;
    const float* x = X + (size_t)wid * 256;
    float v[4]; float s = 0.f;
    #pragma unroll
    for (int j = 0; j < 4; ++j) { v[j] = x[lane + 64*j]; s += v[j]; }
    #pragma unroll
    for (int o = 32; o; o >>= 1) s += __shfl_xor(s, o);
    float mu = s * (1.0f/256.0f);
    float q = 0.f;
    #pragma unroll
    for (int j = 0; j < 4; ++j) { float d = v[j]-mu; q += d*d; }
    #pragma unroll
    for (int o = 32; o; o >>= 1) q += __shfl_xor(q, o);
    float rstd = rsqrtf(q*(1.0f/256.0f) + EPSV);
    #pragma unroll
    for (int j = 0; j < 4; ++j) {
        int c = lane + 64*j;
        float y = (v[j]-mu)*rstd*g[c] + b[c];
        if (pos) y += pos[(size_t)(wid & 1023) * 256 + c];
        if (do_leaky) y = (y >= 0.f) ? y : 0.01f*y;
        Y[(size_t)wid * ldY + colOff + c] = f2bf(y);
    }
}

// ---------------------------------------------------------------------------
// BatchNorm statistics: stats[0..7]=sum, [8..15]=sumsq
// ---------------------------------------------------------------------------
__global__ __launch_bounds__(256) void bn_stats_k(const float* __restrict__ cont,
                                                  float* __restrict__ stats)
{
    __shared__ float ss[8], sq[8];
    int tid = threadIdx.x;
    if (tid < 8) { ss[tid] = 0.f; sq[tid] = 0.f; }
    __syncthreads();
    int gt = blockIdx.x * 256 + tid;
    float s = 0.f, q = 0.f;
    for (int e = gt; e < 32768*8; e += 256*256) { float v = cont[e]; s += v; q += v*v; }
    int f = gt & 7;
    atomicAdd(&ss[f], s);
    atomicAdd(&sq[f], q);
    __syncthreads();
    if (tid < 8) { atomicAdd(&stats[tid], ss[tid]); atomicAdd(&stats[8+tid], sq[tid]); }
}

// ---------------------------------------------------------------------------
// cont path fused: BN-normalize + (8x256 GEMM) + bias + LN + leaky -> bf16
// ---------------------------------------------------------------------------
__global__ __launch_bounds__(256) void cont_k(
    const float* __restrict__ cont, const float* __restrict__ stats,
    const float* __restrict__ bn_g, const float* __restrict__ bn_b,
    const float* __restrict__ W, const float* __restrict__ bias,
    const float* __restrict__ g, const float* __restrict__ bL,
    unsigned short* __restrict__ seq3)
{
    __shared__ float Ws[8][256];
    __shared__ float sscale[8], sshift[8];
    __shared__ float cr[8];
    __shared__ float red[8];
    int tid = threadIdx.x;
    #pragma unroll
    for (int d = 0; d < 8; ++d) Ws[d][tid] = W[d*256 + tid];
    if (tid < 8) {
        float mean = stats[tid] * (1.0f/32768.0f);
        float var  = stats[8+tid] * (1.0f/32768.0f) - mean*mean;
        float r = rsqrtf(var + EPSV);
        float sc = r * bn_g[tid];
        sscale[tid] = sc;
        sshift[tid] = bn_b[tid] - mean*sc;
    }
    __syncthreads();
    int lane = tid & 63, wv = tid >> 6;
    float gv = g[tid], bv = bL[tid], biasv = bias[tid];
    for (int row = blockIdx.x; row < 32768; row += gridDim.x) {
        if (tid < 8) cr[tid] = cont[(size_t)row*8 + tid]*sscale[tid] + sshift[tid];
        __syncthreads();
        float acc = biasv;
        #pragma unroll
        for (int d = 0; d < 8; ++d) acc += cr[d]*Ws[d][tid];
        float s = acc;
        #pragma unroll
        for (int o = 32; o; o >>= 1) s += __shfl_xor(s, o);
        if (lane == 0) red[wv] = s;
        __syncthreads();
        float mu = (red[0]+red[1]+red[2]+red[3]) * (1.0f/256.0f);
        float dc = acc - mu;
        float qv = dc*dc;
        #pragma unroll
        for (int o = 32; o; o >>= 1) qv += __shfl_xor(qv, o);
        if (lane == 0) red[4+wv] = qv;
        __syncthreads();
        float var = (red[4]+red[5]+red[6]+red[7]) * (1.0f/256.0f);
        float y = dc * rsqrtf(var + EPSV) * gv + bv;
        y = (y >= 0.f) ? y : 0.01f*y;
        seq3[(size_t)row*768 + 512 + tid] = f2bf(y);
        __syncthreads();
    }
}

// ---------------------------------------------------------------------------
// key-index construction
// ---------------------------------------------------------------------------
__global__ void build_maps_k(const int* __restrict__ qidx, int* __restrict__ kmap)
{
    __shared__ int flag[1024];
    __shared__ int scan[1024];
    int t = threadIdx.x;
    flag[t] = 0;
    __syncthreads();
    if (t < 128) flag[qidx[t]] = 1;
    __syncthreads();
    int nq = 1 - flag[t];
    scan[t] = nq;
    __syncthreads();
    for (int off = 1; off < 1024; off <<= 1) {
        int v = (t >= off) ? scan[t - off] : 0;
        __syncthreads();
        scan[t] += v;
        __syncthreads();
    }
    if (nq) kmap[scan[t] - 1] = t;
}

__global__ void expand_maps_k(const int* __restrict__ qidx, const int* __restrict__ kmap,
                              int* __restrict__ qmap, int* __restrict__ krmap)
{
    int i = blockIdx.x * 256 + threadIdx.x;
    if (i < 32*128) { int b = i >> 7; int t = i & 127; qmap[i] = b*1024 + qidx[t]; }
    if (i < 32*896) { int b = i / 896; int t = i - b*896; krmap[i] = b*1024 + kmap[t]; }
}

// ---------------------------------------------------------------------------
// mask dtype sniff + canonicalize to uint8[28672]
// ---------------------------------------------------------------------------
__global__ void mask_prep_k(const unsigned char* __restrict__ msrc,
                            unsigned char* __restrict__ mu8)
{
    __shared__ int f_u8, f_i32;
    int t = threadIdx.x;
    if (t == 0) { f_u8 = 0; f_i32 = 0; }
    __syncthreads();
    int lu8 = 0, li32 = 0;
    for (int i = t; i < 28672; i += 256) {
        unsigned char v = msrc[i];
        if (v) {
            if (i & 3) lu8 = 1;
            else if ((i & 7) == 4) li32 = 1;
        }
    }
    if (lu8) atomicOr(&f_u8, 1);
    if (li32) atomicOr(&f_i32, 1);
    __syncthreads();
    int mode = f_u8 ? 0 : (f_i32 ? 1 : 2);
    for (int i = t; i < 28672; i += 256) {
        unsigned char v;
        if (mode == 0)      v = msrc[i] ? 1 : 0;
        else if (mode == 1) v = ((const int*)msrc)[i] ? 1 : 0;
        else                v = ((const long long*)msrc)[i] ? 1 : 0;
        mu8[i] = v;
    }
}

// ---------------------------------------------------------------------------
// MFMA flash attention. Grid 512 = (b, h, qhalf). 4 waves/block.
// Wave w owns 16 q-rows (q-tile qhalf*64 + w*16), iterates 14 tiles of 64 keys.
// Q,K bf16 [row][256]; Vt bf16 [(b*256+c)][896]; out bf16 [row][256].
// QK^T and PV via mfma_f32_16x16x32_bf16; softmax on C-frags in registers;
// P routed through a per-wave 16x72 LDS tile (A-frag re-layout).
// ---------------------------------------------------------------------------
__global__ __launch_bounds__(256) void attn_mfma_k(
    const unsigned short* __restrict__ Qb,
    const unsigned short* __restrict__ Kb,
    const unsigned short* __restrict__ Vtb,
    const unsigned char* __restrict__ mask,
    unsigned short* __restrict__ out)
{
    __shared__ unsigned short Pw[4][16][72];   // per-wave P tile, ld=72 (144B rows)
    const int t = threadIdx.x;
    const int w = t >> 6, l = t & 63;
    const int lr = l & 15, lg = l >> 4;
    const int bx = blockIdx.x;
    const int qh = bx & 1, h = (bx >> 1) & 7, b = bx >> 4;
    const int qrow0 = b*128 + qh*64 + w*16;

    // Q A-frag: lane holds Q[lr][lg*8..+7] of this q-tile's head slice
    short8v qf = *(const short8v*)&Qb[(size_t)(qrow0 + lr)*256 + h*32 + lg*8];

    const unsigned short* Kbase = Kb + (size_t)b*896*256 + h*32;
    const unsigned short* Vbase = Vtb + ((size_t)b*256 + h*32)*896;
    const unsigned char* mrow = mask + b*896;

    float4v O0 = (float4v)0.f, O1 = (float4v)0.f;
    float m[4], lsum[4];
    #pragma unroll
    for (int r = 0; r < 4; ++r) { m[r] = -3.0e38f; lsum[r] = 0.f; }

    short8v kf[4], vf[4];
    int mk[4];
    #pragma unroll
    for (int i = 0; i < 4; ++i) {
        kf[i] = *(const short8v*)&Kbase[(size_t)(i*16 + lr)*256 + lg*8];
        mk[i] = mrow[i*16 + lr];
    }
    #pragma unroll
    for (int kc = 0; kc < 2; ++kc)
        #pragma unroll
        for (int nt = 0; nt < 2; ++nt)
            vf[kc*2+nt] = *(const short8v*)&Vbase[(size_t)(nt*16 + lr)*896 + kc*32 + lg*8];

    for (int kt3 = 0; kt3 < 14; ++kt3) {
        const int kb2 = kt3*64 + 64;
        short8v kf2[4], vf2[4];
        int mk2[4];
        if (kt3 < 13) {
            #pragma unroll
            for (int i = 0; i < 4; ++i) {
                kf2[i] = *(const short8v*)&Kbase[(size_t)(kb2 + i*16 + lr)*256 + lg*8];
                mk2[i] = mrow[kb2 + i*16 + lr];
            }
            #pragma unroll
            for (int kc = 0; kc < 2; ++kc)
                #pragma unroll
                for (int nt = 0; nt < 2; ++nt)
                    vf2[kc*2+nt] = *(const short8v*)&Vbase[(size_t)(nt*16 + lr)*896 + kb2 + kc*32 + lg*8];
        }
        // ---- scores: 4 MFMAs (16q x 64k) ----
        float4v s4[4];
        #pragma unroll
        for (int i = 0; i < 4; ++i)
            s4[i] = __builtin_amdgcn_mfma_f32_16x16x32_bf16(qf, kf[i], (float4v)0.f, 0, 0, 0);
        #pragma unroll
        for (int i = 0; i < 4; ++i)
            #pragma unroll
            for (int r = 0; r < 4; ++r)
                s4[i][r] = mk[i] ? -1e9f : s4[i][r] * 0.17677669529663687f;
        // ---- online softmax on C-frags ----
        float tm[4];
        #pragma unroll
        for (int r = 0; r < 4; ++r)
            tm[r] = fmaxf(fmaxf(s4[0][r], s4[1][r]), fmaxf(s4[2][r], s4[3][r]));
        #pragma unroll
        for (int o = 1; o < 16; o <<= 1)
            #pragma unroll
            for (int r = 0; r < 4; ++r) tm[r] = fmaxf(tm[r], __shfl_xor(tm[r], o));
        float resc[4];
        #pragma unroll
        for (int r = 0; r < 4; ++r) {
            float mn = fmaxf(m[r], tm[r]);
            resc[r] = __expf(m[r] - mn);
            m[r] = mn;
        }
        float rs[4] = {0.f, 0.f, 0.f, 0.f};
        #pragma unroll
        for (int i = 0; i < 4; ++i)
            #pragma unroll
            for (int r = 0; r < 4; ++r) {
                float p = __expf(s4[i][r] - m[r]);
                s4[i][r] = p;
                rs[r] += p;
            }
        #pragma unroll
        for (int o = 1; o < 16; o <<= 1)
            #pragma unroll
            for (int r = 0; r < 4; ++r) rs[r] += __shfl_xor(rs[r], o);
        #pragma unroll
        for (int r = 0; r < 4; ++r) lsum[r] = lsum[r]*resc[r] + rs[r];
        #pragma unroll
        for (int r = 0; r < 4; ++r) { O0[r] *= resc[r]; O1[r] *= resc[r]; }
        // ---- P -> LDS (bf16), C-frag layout -> A-frag layout ----
        #pragma unroll
        for (int i = 0; i < 4; ++i)
            #pragma unroll
            for (int r = 0; r < 4; ++r)
                Pw[w][lg*4 + r][i*16 + lr] = f2bf(s4[i][r]);
        // ---- PV: 4 MFMAs (16q x 32d, K=64 keys in 2 chunks) ----
        #pragma unroll
        for (int kc = 0; kc < 2; ++kc) {
            short8v pf = *(const short8v*)&Pw[w][lr][kc*32 + lg*8];
            O0 = __builtin_amdgcn_mfma_f32_16x16x32_bf16(pf, vf[kc*2+0], O0, 0, 0, 0);
            O1 = __builtin_amdgcn_mfma_f32_16x16x32_bf16(pf, vf[kc*2+1], O1, 0, 0, 0);
        }
        if (kt3 < 13) {
            #pragma unroll
            for (int i = 0; i < 4; ++i) { kf[i] = kf2[i]; mk[i] = mk2[i]; vf[i] = vf2[i]; }
        }
    }
    // ---- epilogue ----
    #pragma unroll
    for (int r = 0; r < 4; ++r) {
        float inv = 1.0f / lsum[r];
        size_t row = (size_t)(qrow0 + lg*4 + r);
        out[row*256 + h*32 + lr]      = f2bf(O0[r] * inv);
        out[row*256 + h*32 + 16 + lr] = f2bf(O1[r] * inv);
    }
}

// ---------------------------------------------------------------------------
extern "C" void kernel_launch(void* const* d_in, const int* in_sizes, int n_in,
                              void* d_out, int out_size, void* d_ws, size_t ws_size,
                              hipStream_t stream)
{
    const float* node       = (const float*)d_in[0];
    const int*   cate       = (const int*)d_in[1];
    const float* cont       = (const float*)d_in[2];
    const int*   qidx       = (const int*)d_in[3];
    const unsigned char* mask = (const unsigned char*)d_in[4];
    const float* cate_table = (const float*)d_in[5];
    const float* pos_emb    = (const float*)d_in[6];
    const float* node_W     = (const float*)d_in[7];
    const float* node_b     = (const float*)d_in[8];
    const float* node_ln_g  = (const float*)d_in[9];
    const float* node_ln_b  = (const float*)d_in[10];
    const float* cate_W     = (const float*)d_in[11];
    const float* cate_b     = (const float*)d_in[12];
    const float* cate_ln_g  = (const float*)d_in[13];
    const float* cate_ln_b  = (const float*)d_in[14];
    const float* bn_g       = (const float*)d_in[15];
    const float* bn_b       = (const float*)d_in[16];
    const float* cont_W     = (const float*)d_in[17];
    const float* cont_b     = (const float*)d_in[18];
    const float* cont_ln_g  = (const float*)d_in[19];
    const float* cont_ln_b  = (const float*)d_in[20];
    const float* comb_W     = (const float*)d_in[21];
    const float* comb_b     = (const float*)d_in[22];
    const float* comb_ln_g  = (const float*)d_in[23];
    const float* comb_ln_b  = (const float*)d_in[24];
    const float* q_W        = (const float*)d_in[25];
    const float* q_b        = (const float*)d_in[26];
    const float* k_W        = (const float*)d_in[27];
    const float* k_b        = (const float*)d_in[28];
    const float* v_W        = (const float*)d_in[29];
    const float* v_b        = (const float*)d_in[30];
    const float* reg_W1     = (const float*)d_in[31];
    const float* reg_b1     = (const float*)d_in[32];
    const float* reg_ln_g   = (const float*)d_in[33];
    const float* reg_ln_b   = (const float*)d_in[34];
    const float* reg_W2     = (const float*)d_in[35];
    const float* reg_b2     = (const float*)d_in[36];

    char* ws = (char*)d_ws;
    unsigned short* seq3bf = (unsigned short*)(ws + 0);          // 32768*768*2
    float*          tmp    = (float*)(ws + 50331648);            // 32768*256*4
    unsigned short* seqbf  = (unsigned short*)(ws + 83886080);   // 32768*256*2
    unsigned short* Qbf    = (unsigned short*)(ws + 100663296);  // 4096*256*2
    unsigned short* Kbf    = (unsigned short*)(ws + 102760448);  // 28672*256*2
    unsigned short* Vtbf   = (unsigned short*)(ws + 117440512);  // 28672*256*2 (transposed)
    unsigned short* AObf   = (unsigned short*)(ws + 132120576);  // 4096*256*2
    unsigned short* Hbf    = (unsigned short*)(ws + 0);          // reuse seq3bf region
    float* stats = (float*)(ws + 165675008);
    int*   kmap  = (int*)  (ws + 165675072);
    int*   qmap  = (int*)  (ws + 165678656);
    int*   krmap = (int*)  (ws + 165695040);
    unsigned char* mu8 = (unsigned char*)(ws + 165809728);
    unsigned short* node_Wt = (unsigned short*)(ws + 165838400);
    unsigned short* cate_Wt = (unsigned short*)(ws + 166362688);
    unsigned short* comb_Wt = (unsigned short*)(ws + 166886976);
    unsigned short* q_Wt    = (unsigned short*)(ws + 167280192);
    unsigned short* k_Wt    = (unsigned short*)(ws + 167411264);
    unsigned short* v_Wt    = (unsigned short*)(ws + 167542336);
    unsigned short* r1_Wt   = (unsigned short*)(ws + 167673408);
    unsigned short* r2_Wt   = (unsigned short*)(ws + 167804480);
    float* outp = (float*)d_out;

    hipMemsetAsync(stats, 0, 64, stream);
    bn_stats_k<<<256, 256, 0, stream>>>(cont, stats);
    mask_prep_k<<<1, 256, 0, stream>>>(mask, mu8);
    wt_k<<<1024, 256, 0, stream>>>(node_W, node_Wt, 1024);
    wt_k<<<1024, 256, 0, stream>>>(cate_W, cate_Wt, 1024);
    wt_k<<<768,  256, 0, stream>>>(comb_W, comb_Wt, 768);
    wt_k<<<256,  256, 0, stream>>>(q_W,  q_Wt,  256);
    wt_k<<<256,  256, 0, stream>>>(k_W,  k_Wt,  256);
    wt_k<<<256,  256, 0, stream>>>(v_W,  v_Wt,  256);
    wt_k<<<256,  256, 0, stream>>>(reg_W1, r1_Wt, 256);
    wt_k<<<256,  256, 0, stream>>>(reg_W2, r2_Wt, 256);

    // node path
    gemm_mfma_k<0,0,0><<<512, 256, 0, stream>>>(32768, 1024, node, nullptr, nullptr, node_Wt, node_b, tmp);
    ln_k<<<8192,256,0,stream>>>(32768, tmp, node_ln_g, node_ln_b, seq3bf, 768, 0, 1, nullptr);
    // cate path
    gemm_mfma_k<1,0,0><<<512, 256, 0, stream>>>(32768, 1024, nullptr, cate, cate_table, cate_Wt, cate_b, tmp);
    ln_k<<<8192,256,0,stream>>>(32768, tmp, cate_ln_g, cate_ln_b, seq3bf, 768, 256, 1, nullptr);
    // cont path
    cont_k<<<2048,256,0,stream>>>(cont, stats, bn_g, bn_b, cont_W, cont_b, cont_ln_g, cont_ln_b, seq3bf);
    // comb
    gemm_mfma_k<0,1,0><<<512, 256, 0, stream>>>(32768, 768, seq3bf, nullptr, nullptr, comb_Wt, comb_b, tmp);
    ln_k<<<8192,256,0,stream>>>(32768, tmp, comb_ln_g, comb_ln_b, seqbf, 256, 0, 0, pos_emb);
    // index maps
    build_maps_k<<<1,1024,0,stream>>>(qidx, kmap);
    expand_maps_k<<<112,256,0,stream>>>(qidx, kmap, qmap, krmap);
    // Q/K/V projections -> bf16 (V transposed per head)
    gemm_mfma_k<2,1,1><<<64,  256, 0, stream>>>(4096,  256, seqbf, qmap,  nullptr, q_Wt, q_b, Qbf);
    gemm_mfma_k<2,1,1><<<448, 256, 0, stream>>>(28672, 256, seqbf, krmap, nullptr, k_Wt, k_b, Kbf);
    gemm_mfma_k<2,1,2><<<448, 256, 0, stream>>>(28672, 256, seqbf, krmap, nullptr, v_Wt, v_b, Vtbf);
    // attention (MFMA flash)
    attn_mfma_k<<<512,256,0,stream>>>(Qbf, Kbf, Vtbf, mu8, AObf);
    // regression head
    gemm_mfma_k<0,1,0><<<64, 256, 0, stream>>>(4096, 256, AObf, nullptr, nullptr, r1_Wt, reg_b1, tmp);
    ln_k<<<1024,256,0,stream>>>(4096, tmp, reg_ln_g, reg_ln_b, Hbf, 256, 0, 1, nullptr);
    gemm_mfma_k<0,1,0><<<64, 256, 0, stream>>>(4096, 256, Hbf, nullptr, nullptr, r2_Wt, reg_b2, outp);
}

// Round 6
// 333.332 us; speedup vs baseline: 5.4621x; 1.4496x over previous
//
#include <hip/hip_runtime.h>
#include <cstdint>

#define EPSV 1e-5f

typedef __attribute__((ext_vector_type(8))) short short8v;   // 8 bf16
typedef __attribute__((ext_vector_type(4))) float float4v;

__device__ inline unsigned short f2bf(float f) {
    union { float f; unsigned int u; } v; v.f = f;
    unsigned int r = v.u + 0x7FFF + ((v.u >> 16) & 1);
    return (unsigned short)(r >> 16);
}

// ---------------------------------------------------------------------------
// All weight transposes+convert in one launch. Wt[n][k] = bf16(W[k][n]), N=256.
// Segments: node(K=1024), cate(1024), comb(768), q,k,v,r1,r2 (256 each).
// ---------------------------------------------------------------------------
__global__ __launch_bounds__(256) void wt_all_k(
    const float* __restrict__ nW, const float* __restrict__ cW, const float* __restrict__ mW,
    const float* __restrict__ qW, const float* __restrict__ kW, const float* __restrict__ vW,
    const float* __restrict__ r1W, const float* __restrict__ r2W,
    unsigned short* __restrict__ nO, unsigned short* __restrict__ cO, unsigned short* __restrict__ mO,
    unsigned short* __restrict__ qO, unsigned short* __restrict__ kO, unsigned short* __restrict__ vO,
    unsigned short* __restrict__ r1O, unsigned short* __restrict__ r2O)
{
    int id = blockIdx.x * 256 + threadIdx.x;
    const float* W; unsigned short* O; int K, base;
    if (id < 262144)      { W = nW; O = nO; K = 1024; base = 0; }
    else if (id < 524288) { W = cW; O = cO; K = 1024; base = 262144; }
    else if (id < 720896) { W = mW; O = mO; K = 768;  base = 524288; }
    else {
        int seg = (id - 720896) >> 16;
        base = 720896 + seg * 65536; K = 256;
        switch (seg) {
            case 0: W = qW;  O = qO;  break;
            case 1: W = kW;  O = kO;  break;
            case 2: W = vW;  O = vO;  break;
            case 3: W = r1W; O = r1O; break;
            default: W = r2W; O = r2O; break;
        }
    }
    int lid = id - base;
    int n = lid / K, k = lid - n * K;
    O[lid] = f2bf(W[(size_t)k * 256 + n]);
}

// ---------------------------------------------------------------------------
// MFMA bf16 GEMM: C[M,256] = A[M,K] @ B[K,256] + bias (+ fused epilogues).
// MODE 0: A direct. MODE 1: cate-table gather (fp32). MODE 2: row gather.
// SRCBF: A is bf16.
// EPI: 0 = f32 out; 1 = bf16 out; 2 = bf16 transposed-V out;
//      3 = LN + leaky -> bf16 (strided ldY/colOff); 4 = LN + pos_emb -> bf16.
// ---------------------------------------------------------------------------
template<int MODE, int SRCBF, int EPI>
__global__ __launch_bounds__(256) void gemm_mfma_k(
    int M, int K,
    const void* __restrict__ Asrc,
    const int* __restrict__ gidx,
    const float* __restrict__ table,
    const unsigned short* __restrict__ Bt,
    const float* __restrict__ bias,
    const float* __restrict__ ln_g,
    const float* __restrict__ ln_b,
    const float* __restrict__ pos,
    void* __restrict__ Cout, int ldY, int colOff)
{
    __shared__ unsigned short As[64][40];
    __shared__ unsigned short Bs[256][40];
    const int t = threadIdx.x;
    const int bm = blockIdx.x * 64;
    const int w = t >> 6;
    const int l = t & 63;
    const int lr = l & 15;
    const int lg = l >> 4;

    float4v acc[4][4];
    #pragma unroll
    for (int i = 0; i < 4; ++i)
        #pragma unroll
        for (int j = 0; j < 4; ++j) acc[i][j] = (float4v)0.f;

    const int arow = t >> 2;
    const int ac8  = (t & 3) * 8;

    for (int kt = 0; kt < K; kt += 32) {
        short8v av;
        if (SRCBF) {
            const unsigned short* ap;
            if (MODE == 2) ap = (const unsigned short*)Asrc + (size_t)gidx[bm + arow] * K + kt + ac8;
            else           ap = (const unsigned short*)Asrc + (size_t)(bm + arow) * K + kt + ac8;
            av = *(const short8v*)ap;
        } else {
            const float* ap;
            if (MODE == 1) {
                int gk = kt + ac8;
                int idx = gidx[(bm + arow) * 4 + (gk >> 8)];
                ap = table + (size_t)idx * 256 + (gk & 255);
            } else if (MODE == 2) {
                ap = (const float*)Asrc + (size_t)gidx[bm + arow] * K + kt + ac8;
            } else {
                ap = (const float*)Asrc + (size_t)(bm + arow) * K + kt + ac8;
            }
            float4 f0 = *(const float4*)ap;
            float4 f1 = *(const float4*)(ap + 4);
            av[0] = (short)f2bf(f0.x); av[1] = (short)f2bf(f0.y);
            av[2] = (short)f2bf(f0.z); av[3] = (short)f2bf(f0.w);
            av[4] = (short)f2bf(f1.x); av[5] = (short)f2bf(f1.y);
            av[6] = (short)f2bf(f1.z); av[7] = (short)f2bf(f1.w);
        }
        const unsigned short* bsrc = Bt + (size_t)t * K + kt;
        short8v b0 = *(const short8v*)(bsrc);
        short8v b1 = *(const short8v*)(bsrc + 8);
        short8v b2 = *(const short8v*)(bsrc + 16);
        short8v b3 = *(const short8v*)(bsrc + 24);

        __syncthreads();
        *(short8v*)&As[arow][ac8] = av;
        *(short8v*)&Bs[t][0]  = b0;
        *(short8v*)&Bs[t][8]  = b1;
        *(short8v*)&Bs[t][16] = b2;
        *(short8v*)&Bs[t][24] = b3;
        __syncthreads();

        short8v af[4], bf[4];
        #pragma unroll
        for (int i = 0; i < 4; ++i) af[i] = *(const short8v*)&As[i*16 + lr][lg*8];
        #pragma unroll
        for (int j = 0; j < 4; ++j) bf[j] = *(const short8v*)&Bs[w*64 + j*16 + lr][lg*8];
        #pragma unroll
        for (int i = 0; i < 4; ++i)
            #pragma unroll
            for (int j = 0; j < 4; ++j)
                acc[i][j] = __builtin_amdgcn_mfma_f32_16x16x32_bf16(af[i], bf[j], acc[i][j], 0, 0, 0);
    }

    // ---- epilogue: D col = lane&15, row = (lane>>4)*4 + reg ----
    float bv[4];
    #pragma unroll
    for (int j = 0; j < 4; ++j) bv[j] = bias[w*64 + j*16 + lr];
    #pragma unroll
    for (int i = 0; i < 4; ++i)
        #pragma unroll
        for (int j = 0; j < 4; ++j)
            #pragma unroll
            for (int r4 = 0; r4 < 4; ++r4) acc[i][j][r4] += bv[j];

    if (EPI <= 2) {
        #pragma unroll
        for (int i = 0; i < 4; ++i) {
            #pragma unroll
            for (int j = 0; j < 4; ++j) {
                int c = w*64 + j*16 + lr;
                #pragma unroll
                for (int r4 = 0; r4 < 4; ++r4) {
                    int rl = i*16 + lg*4 + r4;
                    float val = acc[i][j][r4];
                    if (EPI == 0) {
                        ((float*)Cout)[(size_t)(bm + rl) * 256 + c] = val;
                    } else if (EPI == 1) {
                        ((unsigned short*)Cout)[(size_t)(bm + rl) * 256 + c] = f2bf(val);
                    } else {
                        int vb = bm / 896;
                        int kl = bm - vb * 896 + rl;
                        ((unsigned short*)Cout)[((size_t)vb * 256 + c) * 896 + kl] = f2bf(val);
                    }
                }
            }
        }
    } else {
        // fused LayerNorm over the 256 cols this block owns per row
        __shared__ float redS[64][4];
        __shared__ float redQ[64][4];
        float ps[4][4], qs[4][4];
        #pragma unroll
        for (int i = 0; i < 4; ++i)
            #pragma unroll
            for (int r4 = 0; r4 < 4; ++r4) {
                float a0 = acc[i][0][r4], a1 = acc[i][1][r4],
                      a2 = acc[i][2][r4], a3 = acc[i][3][r4];
                ps[i][r4] = (a0 + a1) + (a2 + a3);
                qs[i][r4] = (a0*a0 + a1*a1) + (a2*a2 + a3*a3);
            }
        #pragma unroll
        for (int o = 1; o < 16; o <<= 1)
            #pragma unroll
            for (int i = 0; i < 4; ++i)
                #pragma unroll
                for (int r4 = 0; r4 < 4; ++r4) {
                    ps[i][r4] += __shfl_xor(ps[i][r4], o);
                    qs[i][r4] += __shfl_xor(qs[i][r4], o);
                }
        if (lr == 0) {
            #pragma unroll
            for (int i = 0; i < 4; ++i)
                #pragma unroll
                for (int r4 = 0; r4 < 4; ++r4) {
                    redS[i*16 + lg*4 + r4][w] = ps[i][r4];
                    redQ[i*16 + lg*4 + r4][w] = qs[i][r4];
                }
        }
        __syncthreads();
        float mu[4][4], rstd[4][4];
        #pragma unroll
        for (int i = 0; i < 4; ++i)
            #pragma unroll
            for (int r4 = 0; r4 < 4; ++r4) {
                int rl = i*16 + lg*4 + r4;
                float s  = (redS[rl][0] + redS[rl][1]) + (redS[rl][2] + redS[rl][3]);
                float qq = (redQ[rl][0] + redQ[rl][1]) + (redQ[rl][2] + redQ[rl][3]);
                float m_ = s * (1.0f/256.0f);
                float var = qq * (1.0f/256.0f) - m_*m_;
                mu[i][r4] = m_;
                rstd[i][r4] = rsqrtf(var + EPSV);
            }
        float gv[4], b2v[4];
        #pragma unroll
        for (int j = 0; j < 4; ++j) {
            int c = w*64 + j*16 + lr;
            gv[j] = ln_g[c];
            b2v[j] = ln_b[c];
        }
        #pragma unroll
        for (int i = 0; i < 4; ++i) {
            #pragma unroll
            for (int j = 0; j < 4; ++j) {
                int c = w*64 + j*16 + lr;
                #pragma unroll
                for (int r4 = 0; r4 < 4; ++r4) {
                    int row = bm + i*16 + lg*4 + r4;
                    float y = (acc[i][j][r4] - mu[i][r4]) * rstd[i][r4] * gv[j] + b2v[j];
                    if (EPI == 3) y = (y >= 0.f) ? y : 0.01f*y;
                    if (EPI == 4) y += pos[(size_t)(row & 1023) * 256 + c];
                    ((unsigned short*)Cout)[(size_t)row * ldY + colOff + c] = f2bf(y);
                }
            }
        }
    }
}

// ---------------------------------------------------------------------------
// BatchNorm statistics: stats[0..7]=sum, [8..15]=sumsq
// ---------------------------------------------------------------------------
__global__ __launch_bounds__(256) void bn_stats_k(const float* __restrict__ cont,
                                                  float* __restrict__ stats)
{
    __shared__ float ss[8], sq[8];
    int tid = threadIdx.x;
    if (tid < 8) { ss[tid] = 0.f; sq[tid] = 0.f; }
    __syncthreads();
    int gt = blockIdx.x * 256 + tid;
    float s = 0.f, q = 0.f;
    for (int e = gt; e < 32768*8; e += 256*256) { float v = cont[e]; s += v; q += v*v; }
    int f = gt & 7;
    atomicAdd(&ss[f], s);
    atomicAdd(&sq[f], q);
    __syncthreads();
    if (tid < 8) { atomicAdd(&stats[tid], ss[tid]); atomicAdd(&stats[8+tid], sq[tid]); }
}

// ---------------------------------------------------------------------------
// cont path fused: BN-normalize + (8x256 GEMM) + bias + LN + leaky -> bf16
// ---------------------------------------------------------------------------
__global__ __launch_bounds__(256) void cont_k(
    const float* __restrict__ cont, const float* __restrict__ stats,
    const float* __restrict__ bn_g, const float* __restrict__ bn_b,
    const float* __restrict__ W, const float* __restrict__ bias,
    const float* __restrict__ g, const float* __restrict__ bL,
    unsigned short* __restrict__ seq3)
{
    __shared__ float Ws[8][256];
    __shared__ float sscale[8], sshift[8];
    __shared__ float cr[8];
    __shared__ float red[8];
    int tid = threadIdx.x;
    #pragma unroll
    for (int d = 0; d < 8; ++d) Ws[d][tid] = W[d*256 + tid];
    if (tid < 8) {
        float mean = stats[tid] * (1.0f/32768.0f);
        float var  = stats[8+tid] * (1.0f/32768.0f) - mean*mean;
        float r = rsqrtf(var + EPSV);
        float sc = r * bn_g[tid];
        sscale[tid] = sc;
        sshift[tid] = bn_b[tid] - mean*sc;
    }
    __syncthreads();
    int lane = tid & 63, wv = tid >> 6;
    float gv = g[tid], bv = bL[tid], biasv = bias[tid];
    for (int row = blockIdx.x; row < 32768; row += gridDim.x) {
        if (tid < 8) cr[tid] = cont[(size_t)row*8 + tid]*sscale[tid] + sshift[tid];
        __syncthreads();
        float acc = biasv;
        #pragma unroll
        for (int d = 0; d < 8; ++d) acc += cr[d]*Ws[d][tid];
        float s = acc;
        #pragma unroll
        for (int o = 32; o; o >>= 1) s += __shfl_xor(s, o);
        if (lane == 0) red[wv] = s;
        __syncthreads();
        float mu = (red[0]+red[1]+red[2]+red[3]) * (1.0f/256.0f);
        float dc = acc - mu;
        float qv = dc*dc;
        #pragma unroll
        for (int o = 32; o; o >>= 1) qv += __shfl_xor(qv, o);
        if (lane == 0) red[4+wv] = qv;
        __syncthreads();
        float var = (red[4]+red[5]+red[6]+red[7]) * (1.0f/256.0f);
        float y = dc * rsqrtf(var + EPSV) * gv + bv;
        y = (y >= 0.f) ? y : 0.01f*y;
        seq3[(size_t)row*768 + 512 + tid] = f2bf(y);
        __syncthreads();
    }
}

// ---------------------------------------------------------------------------
// key-index construction
// ---------------------------------------------------------------------------
__global__ void build_maps_k(const int* __restrict__ qidx, int* __restrict__ kmap)
{
    __shared__ int flag[1024];
    __shared__ int scan[1024];
    int t = threadIdx.x;
    flag[t] = 0;
    __syncthreads();
    if (t < 128) flag[qidx[t]] = 1;
    __syncthreads();
    int nq = 1 - flag[t];
    scan[t] = nq;
    __syncthreads();
    for (int off = 1; off < 1024; off <<= 1) {
        int v = (t >= off) ? scan[t - off] : 0;
        __syncthreads();
        scan[t] += v;
        __syncthreads();
    }
    if (nq) kmap[scan[t] - 1] = t;
}

__global__ void expand_maps_k(const int* __restrict__ qidx, const int* __restrict__ kmap,
                              int* __restrict__ qmap, int* __restrict__ krmap)
{
    int i = blockIdx.x * 256 + threadIdx.x;
    if (i < 32*128) { int b = i >> 7; int t = i & 127; qmap[i] = b*1024 + qidx[t]; }
    if (i < 32*896) { int b = i / 896; int t = i - b*896; krmap[i] = b*1024 + kmap[t]; }
}

// ---------------------------------------------------------------------------
// mask dtype sniff (parallel): flags[0]=u8 evidence, flags[1]=i32 evidence
// ---------------------------------------------------------------------------
__global__ __launch_bounds__(256) void mask_sniff_k(const unsigned char* __restrict__ msrc,
                                                    int* __restrict__ flags)
{
    int i = blockIdx.x * 256 + threadIdx.x;   // grid covers exactly 28672
    unsigned char v = msrc[i];
    bool u8  = v && (i & 3);
    bool i32 = v && !(i & 3) && ((i & 7) == 4);
    unsigned long long bu = __ballot(u8);
    unsigned long long bi = __ballot(i32);
    if ((threadIdx.x & 63) == 0) {
        if (bu) atomicOr(&flags[0], 1);
        if (bi) atomicOr(&flags[1], 1);
    }
}

__global__ __launch_bounds__(256) void mask_conv_k(const unsigned char* __restrict__ msrc,
                                                   const int* __restrict__ flags,
                                                   unsigned char* __restrict__ mu8)
{
    int i = blockIdx.x * 256 + threadIdx.x;
    int mode = flags[0] ? 0 : (flags[1] ? 1 : 2);
    unsigned char v;
    if (mode == 0)      v = msrc[i] ? 1 : 0;
    else if (mode == 1) v = ((const int*)msrc)[i] ? 1 : 0;
    else                v = ((const long long*)msrc)[i] ? 1 : 0;
    mu8[i] = v;
}

// ---------------------------------------------------------------------------
// MFMA flash attention. Grid 512 = (b, h, qhalf). 4 waves/block.
// ---------------------------------------------------------------------------
__global__ __launch_bounds__(256) void attn_mfma_k(
    const unsigned short* __restrict__ Qb,
    const unsigned short* __restrict__ Kb,
    const unsigned short* __restrict__ Vtb,
    const unsigned char* __restrict__ mask,
    unsigned short* __restrict__ out)
{
    __shared__ unsigned short Pw[4][16][72];
    const int t = threadIdx.x;
    const int w = t >> 6, l = t & 63;
    const int lr = l & 15, lg = l >> 4;
    const int bx = blockIdx.x;
    const int qh = bx & 1, h = (bx >> 1) & 7, b = bx >> 4;
    const int qrow0 = b*128 + qh*64 + w*16;

    short8v qf = *(const short8v*)&Qb[(size_t)(qrow0 + lr)*256 + h*32 + lg*8];

    const unsigned short* Kbase = Kb + (size_t)b*896*256 + h*32;
    const unsigned short* Vbase = Vtb + ((size_t)b*256 + h*32)*896;
    const unsigned char* mrow = mask + b*896;

    float4v O0 = (float4v)0.f, O1 = (float4v)0.f;
    float m[4], lsum[4];
    #pragma unroll
    for (int r = 0; r < 4; ++r) { m[r] = -3.0e38f; lsum[r] = 0.f; }

    short8v kf[4], vf[4];
    int mk[4];
    #pragma unroll
    for (int i = 0; i < 4; ++i) {
        kf[i] = *(const short8v*)&Kbase[(size_t)(i*16 + lr)*256 + lg*8];
        mk[i] = mrow[i*16 + lr];
    }
    #pragma unroll
    for (int kc = 0; kc < 2; ++kc)
        #pragma unroll
        for (int nt = 0; nt < 2; ++nt)
            vf[kc*2+nt] = *(const short8v*)&Vbase[(size_t)(nt*16 + lr)*896 + kc*32 + lg*8];

    for (int kt3 = 0; kt3 < 14; ++kt3) {
        const int kb2 = kt3*64 + 64;
        short8v kf2[4], vf2[4];
        int mk2[4];
        if (kt3 < 13) {
            #pragma unroll
            for (int i = 0; i < 4; ++i) {
                kf2[i] = *(const short8v*)&Kbase[(size_t)(kb2 + i*16 + lr)*256 + lg*8];
                mk2[i] = mrow[kb2 + i*16 + lr];
            }
            #pragma unroll
            for (int kc = 0; kc < 2; ++kc)
                #pragma unroll
                for (int nt = 0; nt < 2; ++nt)
                    vf2[kc*2+nt] = *(const short8v*)&Vbase[(size_t)(nt*16 + lr)*896 + kb2 + kc*32 + lg*8];
        }
        float4v s4[4];
        #pragma unroll
        for (int i = 0; i < 4; ++i)
            s4[i] = __builtin_amdgcn_mfma_f32_16x16x32_bf16(qf, kf[i], (float4v)0.f, 0, 0, 0);
        #pragma unroll
        for (int i = 0; i < 4; ++i)
            #pragma unroll
            for (int r = 0; r < 4; ++r)
                s4[i][r] = mk[i] ? -1e9f : s4[i][r] * 0.17677669529663687f;
        float tm[4];
        #pragma unroll
        for (int r = 0; r < 4; ++r)
            tm[r] = fmaxf(fmaxf(s4[0][r], s4[1][r]), fmaxf(s4[2][r], s4[3][r]));
        #pragma unroll
        for (int o = 1; o < 16; o <<= 1)
            #pragma unroll
            for (int r = 0; r < 4; ++r) tm[r] = fmaxf(tm[r], __shfl_xor(tm[r], o));
        float resc[4];
        #pragma unroll
        for (int r = 0; r < 4; ++r) {
            float mn = fmaxf(m[r], tm[r]);
            resc[r] = __expf(m[r] - mn);
            m[r] = mn;
        }
        float rs[4] = {0.f, 0.f, 0.f, 0.f};
        #pragma unroll
        for (int i = 0; i < 4; ++i)
            #pragma unroll
            for (int r = 0; r < 4; ++r) {
                float p = __expf(s4[i][r] - m[r]);
                s4[i][r] = p;
                rs[r] += p;
            }
        #pragma unroll
        for (int o = 1; o < 16; o <<= 1)
            #pragma unroll
            for (int r = 0; r < 4; ++r) rs[r] += __shfl_xor(rs[r], o);
        #pragma unroll
        for (int r = 0; r < 4; ++r) lsum[r] = lsum[r]*resc[r] + rs[r];
        #pragma unroll
        for (int r = 0; r < 4; ++r) { O0[r] *= resc[r]; O1[r] *= resc[r]; }
        #pragma unroll
        for (int i = 0; i < 4; ++i)
            #pragma unroll
            for (int r = 0; r < 4; ++r)
                Pw[w][lg*4 + r][i*16 + lr] = f2bf(s4[i][r]);
        #pragma unroll
        for (int kc = 0; kc < 2; ++kc) {
            short8v pf = *(const short8v*)&Pw[w][lr][kc*32 + lg*8];
            O0 = __builtin_amdgcn_mfma_f32_16x16x32_bf16(pf, vf[kc*2+0], O0, 0, 0, 0);
            O1 = __builtin_amdgcn_mfma_f32_16x16x32_bf16(pf, vf[kc*2+1], O1, 0, 0, 0);
        }
        if (kt3 < 13) {
            #pragma unroll
            for (int i = 0; i < 4; ++i) { kf[i] = kf2[i]; mk[i] = mk2[i]; vf[i] = vf2[i]; }
        }
    }
    #pragma unroll
    for (int r = 0; r < 4; ++r) {
        float inv = 1.0f / lsum[r];
        size_t row = (size_t)(qrow0 + lg*4 + r);
        out[row*256 + h*32 + lr]      = f2bf(O0[r] * inv);
        out[row*256 + h*32 + 16 + lr] = f2bf(O1[r] * inv);
    }
}

// ---------------------------------------------------------------------------
extern "C" void kernel_launch(void* const* d_in, const int* in_sizes, int n_in,
                              void* d_out, int out_size, void* d_ws, size_t ws_size,
                              hipStream_t stream)
{
    const float* node       = (const float*)d_in[0];
    const int*   cate       = (const int*)d_in[1];
    const float* cont       = (const float*)d_in[2];
    const int*   qidx       = (const int*)d_in[3];
    const unsigned char* mask = (const unsigned char*)d_in[4];
    const float* cate_table = (const float*)d_in[5];
    const float* pos_emb    = (const float*)d_in[6];
    const float* node_W     = (const float*)d_in[7];
    const float* node_b     = (const float*)d_in[8];
    const float* node_ln_g  = (const float*)d_in[9];
    const float* node_ln_b  = (const float*)d_in[10];
    const float* cate_W     = (const float*)d_in[11];
    const float* cate_b     = (const float*)d_in[12];
    const float* cate_ln_g  = (const float*)d_in[13];
    const float* cate_ln_b  = (const float*)d_in[14];
    const float* bn_g       = (const float*)d_in[15];
    const float* bn_b       = (const float*)d_in[16];
    const float* cont_W     = (const float*)d_in[17];
    const float* cont_b     = (const float*)d_in[18];
    const float* cont_ln_g  = (const float*)d_in[19];
    const float* cont_ln_b  = (const float*)d_in[20];
    const float* comb_W     = (const float*)d_in[21];
    const float* comb_b     = (const float*)d_in[22];
    const float* comb_ln_g  = (const float*)d_in[23];
    const float* comb_ln_b  = (const float*)d_in[24];
    const float* q_W        = (const float*)d_in[25];
    const float* q_b        = (const float*)d_in[26];
    const float* k_W        = (const float*)d_in[27];
    const float* k_b        = (const float*)d_in[28];
    const float* v_W        = (const float*)d_in[29];
    const float* v_b        = (const float*)d_in[30];
    const float* reg_W1     = (const float*)d_in[31];
    const float* reg_b1     = (const float*)d_in[32];
    const float* reg_ln_g   = (const float*)d_in[33];
    const float* reg_ln_b   = (const float*)d_in[34];
    const float* reg_W2     = (const float*)d_in[35];
    const float* reg_b2     = (const float*)d_in[36];

    char* ws = (char*)d_ws;
    unsigned short* seq3bf = (unsigned short*)(ws + 0);          // 32768*768*2
    unsigned short* seqbf  = (unsigned short*)(ws + 83886080);   // 32768*256*2
    unsigned short* Qbf    = (unsigned short*)(ws + 100663296);  // 4096*256*2
    unsigned short* Kbf    = (unsigned short*)(ws + 102760448);  // 28672*256*2
    unsigned short* Vtbf   = (unsigned short*)(ws + 117440512);  // 28672*256*2 (transposed)
    unsigned short* AObf   = (unsigned short*)(ws + 132120576);  // 4096*256*2
    unsigned short* Hbf    = (unsigned short*)(ws + 0);          // reuse seq3bf region
    float* stats = (float*)(ws + 165675008);                     // 16 f
    int*   flags = (int*)  (ws + 165675072);                     // 2 i (zeroed with stats)
    int*   kmap  = (int*)  (ws + 165675136);
    int*   qmap  = (int*)  (ws + 165678720);
    int*   krmap = (int*)  (ws + 165695104);
    unsigned char* mu8 = (unsigned char*)(ws + 165809792);
    unsigned short* node_Wt = (unsigned short*)(ws + 165838464);
    unsigned short* cate_Wt = (unsigned short*)(ws + 166362752);
    unsigned short* comb_Wt = (unsigned short*)(ws + 166887040);
    unsigned short* q_Wt    = (unsigned short*)(ws + 167280256);
    unsigned short* k_Wt    = (unsigned short*)(ws + 167411328);
    unsigned short* v_Wt    = (unsigned short*)(ws + 167542400);
    unsigned short* r1_Wt   = (unsigned short*)(ws + 167673472);
    unsigned short* r2_Wt   = (unsigned short*)(ws + 167804544);
    float* outp = (float*)d_out;

    hipMemsetAsync(stats, 0, 128, stream);
    bn_stats_k<<<256, 256, 0, stream>>>(cont, stats);
    mask_sniff_k<<<112, 256, 0, stream>>>(mask, flags);
    mask_conv_k<<<112, 256, 0, stream>>>(mask, flags, mu8);
    wt_all_k<<<4096, 256, 0, stream>>>(node_W, cate_W, comb_W, q_W, k_W, v_W, reg_W1, reg_W2,
                                       node_Wt, cate_Wt, comb_Wt, q_Wt, k_Wt, v_Wt, r1_Wt, r2_Wt);

    // node path (GEMM + LN + leaky fused)
    gemm_mfma_k<0,0,3><<<512, 256, 0, stream>>>(32768, 1024, node, nullptr, nullptr, node_Wt,
        node_b, node_ln_g, node_ln_b, nullptr, seq3bf, 768, 0);
    // cate path
    gemm_mfma_k<1,0,3><<<512, 256, 0, stream>>>(32768, 1024, nullptr, cate, cate_table, cate_Wt,
        cate_b, cate_ln_g, cate_ln_b, nullptr, seq3bf, 768, 256);
    // cont path
    cont_k<<<2048,256,0,stream>>>(cont, stats, bn_g, bn_b, cont_W, cont_b, cont_ln_g, cont_ln_b, seq3bf);
    // comb (GEMM + LN + pos fused)
    gemm_mfma_k<0,1,4><<<512, 256, 0, stream>>>(32768, 768, seq3bf, nullptr, nullptr, comb_Wt,
        comb_b, comb_ln_g, comb_ln_b, pos_emb, seqbf, 256, 0);
    // index maps
    build_maps_k<<<1,1024,0,stream>>>(qidx, kmap);
    expand_maps_k<<<112,256,0,stream>>>(qidx, kmap, qmap, krmap);
    // Q/K/V projections -> bf16 (V transposed per head)
    gemm_mfma_k<2,1,1><<<64,  256, 0, stream>>>(4096,  256, seqbf, qmap,  nullptr, q_Wt,
        q_b, nullptr, nullptr, nullptr, Qbf, 256, 0);
    gemm_mfma_k<2,1,1><<<448, 256, 0, stream>>>(28672, 256, seqbf, krmap, nullptr, k_Wt,
        k_b, nullptr, nullptr, nullptr, Kbf, 256, 0);
    gemm_mfma_k<2,1,2><<<448, 256, 0, stream>>>(28672, 256, seqbf, krmap, nullptr, v_Wt,
        v_b, nullptr, nullptr, nullptr, Vtbf, 256, 0);
    // attention (MFMA flash)
    attn_mfma_k<<<512,256,0,stream>>>(Qbf, Kbf, Vtbf, mu8, AObf);
    // regression head
    gemm_mfma_k<0,1,3><<<64, 256, 0, stream>>>(4096, 256, AObf, nullptr, nullptr, r1_Wt,
        reg_b1, reg_ln_g, reg_ln_b, nullptr, Hbf, 256, 0);
    gemm_mfma_k<0,1,0><<<64, 256, 0, stream>>>(4096, 256, Hbf, nullptr, nullptr, r2_Wt,
        reg_b2, nullptr, nullptr, nullptr, outp, 256, 0);
}

// Round 7
// 313.355 us; speedup vs baseline: 5.8104x; 1.0638x over previous
//
#include <hip/hip_runtime.h>
#include <cstdint>

#define EPSV 1e-5f

typedef __attribute__((ext_vector_type(8))) short short8v;   // 8 bf16
typedef __attribute__((ext_vector_type(4))) float float4v;

__device__ inline unsigned short f2bf(float f) {
    union { float f; unsigned int u; } v; v.f = f;
    unsigned int r = v.u + 0x7FFF + ((v.u >> 16) & 1);
    return (unsigned short)(r >> 16);
}

// ---------------------------------------------------------------------------
// Weight transpose+convert, coalesced via 64x64 LDS tiles.
// Wt[n][k] = bf16(W[k][n]); N = 256. 256 tiles total:
// 0-63 node(K=1024), 64-127 cate(1024), 128-175 comb(768),
// 176+ : q,k,v,r1,r2 (K=256, 16 tiles each).
// ---------------------------------------------------------------------------
__global__ __launch_bounds__(256) void wt_all_k(
    const float* __restrict__ nW, const float* __restrict__ cW, const float* __restrict__ mW,
    const float* __restrict__ qW, const float* __restrict__ kW, const float* __restrict__ vW,
    const float* __restrict__ r1W, const float* __restrict__ r2W,
    unsigned short* __restrict__ nO, unsigned short* __restrict__ cO, unsigned short* __restrict__ mO,
    unsigned short* __restrict__ qO, unsigned short* __restrict__ kO, unsigned short* __restrict__ vO,
    unsigned short* __restrict__ r1O, unsigned short* __restrict__ r2O)
{
    __shared__ float T[64][65];
    int bid = blockIdx.x;
    const float* W; unsigned short* O; int K, tile;
    if (bid < 64)       { W = nW; O = nO; K = 1024; tile = bid; }
    else if (bid < 128) { W = cW; O = cO; K = 1024; tile = bid - 64; }
    else if (bid < 176) { W = mW; O = mO; K = 768;  tile = bid - 128; }
    else {
        int s = (bid - 176) >> 4; tile = (bid - 176) & 15; K = 256;
        switch (s) {
            case 0: W = qW;  O = qO;  break;
            case 1: W = kW;  O = kO;  break;
            case 2: W = vW;  O = vO;  break;
            case 3: W = r1W; O = r1O; break;
            default: W = r2W; O = r2O; break;
        }
    }
    int kTiles = K >> 6;
    int k0 = (tile % kTiles) * 64, n0 = (tile / kTiles) * 64;
    int c = threadIdx.x & 63, r4 = threadIdx.x >> 6;
    #pragma unroll
    for (int rr = 0; rr < 64; rr += 4) {
        int r = rr + r4;
        T[r][c] = W[(size_t)(k0 + r) * 256 + n0 + c];
    }
    __syncthreads();
    #pragma unroll
    for (int rr = 0; rr < 64; rr += 4) {
        int n = rr + r4;
        O[(size_t)(n0 + n) * K + k0 + c] = f2bf(T[c][n]);
    }
}

// ---------------------------------------------------------------------------
// staging registers for the GEMM pipeline
// ---------------------------------------------------------------------------
struct StageRegs {
    float4 f0, f1;     // fp32 A path
    short8v av;        // bf16 A path
    short8v b0, b1, b2, b3;
};

template<int MODE, int SRCBF>
__device__ inline void stage_issue(StageRegs& R, int kt,
    const float* apf, const unsigned short* apb, const float* table,
    const int4 idx4, int ac8, const unsigned short* bp)
{
    if (SRCBF) {
        R.av = *(const short8v*)(apb + kt);
    } else if (MODE == 1) {
        int g = kt >> 8;
        int idx = (g == 0) ? idx4.x : (g == 1) ? idx4.y : (g == 2) ? idx4.z : idx4.w;
        const float* ap = table + (size_t)idx * 256 + (kt & 255) + ac8;
        R.f0 = *(const float4*)ap;
        R.f1 = *(const float4*)(ap + 4);
    } else {
        R.f0 = *(const float4*)(apf + kt);
        R.f1 = *(const float4*)(apf + kt + 4);
    }
    const unsigned short* bs = bp + kt;
    R.b0 = *(const short8v*)bs;
    R.b1 = *(const short8v*)(bs + 8);
    R.b2 = *(const short8v*)(bs + 16);
    R.b3 = *(const short8v*)(bs + 24);
}

template<int SRCBF>
__device__ inline void stage_write(const StageRegs& R, int arow, int ac8, int t,
    unsigned short (*As)[40], unsigned short (*Bs)[40])
{
    short8v av;
    if (SRCBF) {
        av = R.av;
    } else {
        av[0] = (short)f2bf(R.f0.x); av[1] = (short)f2bf(R.f0.y);
        av[2] = (short)f2bf(R.f0.z); av[3] = (short)f2bf(R.f0.w);
        av[4] = (short)f2bf(R.f1.x); av[5] = (short)f2bf(R.f1.y);
        av[6] = (short)f2bf(R.f1.z); av[7] = (short)f2bf(R.f1.w);
    }
    *(short8v*)&As[arow][ac8] = av;
    *(short8v*)&Bs[t][0]  = R.b0;
    *(short8v*)&Bs[t][8]  = R.b1;
    *(short8v*)&Bs[t][16] = R.b2;
    *(short8v*)&Bs[t][24] = R.b3;
}

__device__ inline void compute_step(float4v (&acc)[4][4], int lr, int lg, int w,
    unsigned short (*As)[40], unsigned short (*Bs)[40])
{
    short8v af[4], bf[4];
    #pragma unroll
    for (int i = 0; i < 4; ++i) af[i] = *(const short8v*)&As[i*16 + lr][lg*8];
    #pragma unroll
    for (int j = 0; j < 4; ++j) bf[j] = *(const short8v*)&Bs[w*64 + j*16 + lr][lg*8];
    #pragma unroll
    for (int i = 0; i < 4; ++i)
        #pragma unroll
        for (int j = 0; j < 4; ++j)
            acc[i][j] = __builtin_amdgcn_mfma_f32_16x16x32_bf16(af[i], bf[j], acc[i][j], 0, 0, 0);
}

// ---------------------------------------------------------------------------
// MFMA bf16 GEMM: C[M,256] = A[M,K] @ B[K,256] + bias (+ fused epilogues).
// MODE 0: A direct. MODE 1: cate-table gather (fp32). MODE 2: row gather.
// SRCBF: A is bf16.
// EPI: 0 f32 out; 1 bf16 out; 2 bf16 transposed-V out; 3 LN+leaky; 4 LN+pos.
// K must be a multiple of 64 (1024/768/256 here).
// Ping-pong register prefetch: loads for tile t+1 are in flight across the
// whole compute of tile t (max hiding achievable under __syncthreads drain).
// ---------------------------------------------------------------------------
template<int MODE, int SRCBF, int EPI>
__global__ __launch_bounds__(256) void gemm_mfma_k(
    int M, int K,
    const void* __restrict__ Asrc,
    const int* __restrict__ gidx,
    const float* __restrict__ table,
    const unsigned short* __restrict__ Bt,
    const float* __restrict__ bias,
    const float* __restrict__ ln_g,
    const float* __restrict__ ln_b,
    const float* __restrict__ pos,
    void* __restrict__ Cout, int ldY, int colOff)
{
    __shared__ unsigned short As[64][40];
    __shared__ unsigned short Bs[256][40];
    const int t = threadIdx.x;
    const int bm = blockIdx.x * 64;
    const int w = t >> 6;
    const int l = t & 63;
    const int lr = l & 15;
    const int lg = l >> 4;
    const int arow = t >> 2;
    const int ac8  = (t & 3) * 8;

    // per-thread A base (hoisted gather indices)
    const float* apf = nullptr;
    const unsigned short* apb = nullptr;
    int4 idx4 = {0, 0, 0, 0};
    if (MODE == 1) {
        idx4 = *(const int4*)&gidx[(bm + arow) * 4];
    } else if (MODE == 2) {
        int srow = gidx[bm + arow];
        if (SRCBF) apb = (const unsigned short*)Asrc + (size_t)srow * K + ac8;
        else       apf = (const float*)Asrc + (size_t)srow * K + ac8;
    } else {
        if (SRCBF) apb = (const unsigned short*)Asrc + (size_t)(bm + arow) * K + ac8;
        else       apf = (const float*)Asrc + (size_t)(bm + arow) * K + ac8;
    }
    const unsigned short* bp = Bt + (size_t)t * K;

    float4v acc[4][4];
    #pragma unroll
    for (int i = 0; i < 4; ++i)
        #pragma unroll
        for (int j = 0; j < 4; ++j) acc[i][j] = (float4v)0.f;

    StageRegs RA, RB;
    stage_issue<MODE, SRCBF>(RA, 0, apf, apb, table, idx4, ac8, bp);

    for (int kt = 0; kt < K; kt += 64) {
        // --- sub-step a: tile kt (regs RA), prefetch kt+32 -> RB ---
        __syncthreads();
        stage_write<SRCBF>(RA, arow, ac8, t, As, Bs);
        __syncthreads();
        stage_issue<MODE, SRCBF>(RB, kt + 32, apf, apb, table, idx4, ac8, bp);
        compute_step(acc, lr, lg, w, As, Bs);
        // --- sub-step b: tile kt+32 (regs RB), prefetch kt+64 -> RA ---
        __syncthreads();
        stage_write<SRCBF>(RB, arow, ac8, t, As, Bs);
        __syncthreads();
        if (kt + 64 < K)
            stage_issue<MODE, SRCBF>(RA, kt + 64, apf, apb, table, idx4, ac8, bp);
        compute_step(acc, lr, lg, w, As, Bs);
    }

    // ---- epilogue: D col = lane&15, row = (lane>>4)*4 + reg ----
    float bv[4];
    #pragma unroll
    for (int j = 0; j < 4; ++j) bv[j] = bias[w*64 + j*16 + lr];
    #pragma unroll
    for (int i = 0; i < 4; ++i)
        #pragma unroll
        for (int j = 0; j < 4; ++j)
            #pragma unroll
            for (int r4 = 0; r4 < 4; ++r4) acc[i][j][r4] += bv[j];

    if (EPI <= 2) {
        #pragma unroll
        for (int i = 0; i < 4; ++i) {
            #pragma unroll
            for (int j = 0; j < 4; ++j) {
                int c = w*64 + j*16 + lr;
                #pragma unroll
                for (int r4 = 0; r4 < 4; ++r4) {
                    int rl = i*16 + lg*4 + r4;
                    float val = acc[i][j][r4];
                    if (EPI == 0) {
                        ((float*)Cout)[(size_t)(bm + rl) * 256 + c] = val;
                    } else if (EPI == 1) {
                        ((unsigned short*)Cout)[(size_t)(bm + rl) * 256 + c] = f2bf(val);
                    } else {
                        int vb = bm / 896;
                        int kl = bm - vb * 896 + rl;
                        ((unsigned short*)Cout)[((size_t)vb * 256 + c) * 896 + kl] = f2bf(val);
                    }
                }
            }
        }
    } else {
        __shared__ float redS[64][4];
        __shared__ float redQ[64][4];
        float ps[4][4], qs[4][4];
        #pragma unroll
        for (int i = 0; i < 4; ++i)
            #pragma unroll
            for (int r4 = 0; r4 < 4; ++r4) {
                float a0 = acc[i][0][r4], a1 = acc[i][1][r4],
                      a2 = acc[i][2][r4], a3 = acc[i][3][r4];
                ps[i][r4] = (a0 + a1) + (a2 + a3);
                qs[i][r4] = (a0*a0 + a1*a1) + (a2*a2 + a3*a3);
            }
        #pragma unroll
        for (int o = 1; o < 16; o <<= 1)
            #pragma unroll
            for (int i = 0; i < 4; ++i)
                #pragma unroll
                for (int r4 = 0; r4 < 4; ++r4) {
                    ps[i][r4] += __shfl_xor(ps[i][r4], o);
                    qs[i][r4] += __shfl_xor(qs[i][r4], o);
                }
        if (lr == 0) {
            #pragma unroll
            for (int i = 0; i < 4; ++i)
                #pragma unroll
                for (int r4 = 0; r4 < 4; ++r4) {
                    redS[i*16 + lg*4 + r4][w] = ps[i][r4];
                    redQ[i*16 + lg*4 + r4][w] = qs[i][r4];
                }
        }
        __syncthreads();
        float mu[4][4], rstd[4][4];
        #pragma unroll
        for (int i = 0; i < 4; ++i)
            #pragma unroll
            for (int r4 = 0; r4 < 4; ++r4) {
                int rl = i*16 + lg*4 + r4;
                float s  = (redS[rl][0] + redS[rl][1]) + (redS[rl][2] + redS[rl][3]);
                float qq = (redQ[rl][0] + redQ[rl][1]) + (redQ[rl][2] + redQ[rl][3]);
                float m_ = s * (1.0f/256.0f);
                float var = qq * (1.0f/256.0f) - m_*m_;
                mu[i][r4] = m_;
                rstd[i][r4] = rsqrtf(var + EPSV);
            }
        float gv[4], b2v[4];
        #pragma unroll
        for (int j = 0; j < 4; ++j) {
            int c = w*64 + j*16 + lr;
            gv[j] = ln_g[c];
            b2v[j] = ln_b[c];
        }
        #pragma unroll
        for (int i = 0; i < 4; ++i) {
            #pragma unroll
            for (int j = 0; j < 4; ++j) {
                int c = w*64 + j*16 + lr;
                #pragma unroll
                for (int r4 = 0; r4 < 4; ++r4) {
                    int row = bm + i*16 + lg*4 + r4;
                    float y = (acc[i][j][r4] - mu[i][r4]) * rstd[i][r4] * gv[j] + b2v[j];
                    if (EPI == 3) y = (y >= 0.f) ? y : 0.01f*y;
                    if (EPI == 4) y += pos[(size_t)(row & 1023) * 256 + c];
                    ((unsigned short*)Cout)[(size_t)row * ldY + colOff + c] = f2bf(y);
                }
            }
        }
    }
}

// ---------------------------------------------------------------------------
// BatchNorm statistics: stats[0..7]=sum, [8..15]=sumsq
// ---------------------------------------------------------------------------
__global__ __launch_bounds__(256) void bn_stats_k(const float* __restrict__ cont,
                                                  float* __restrict__ stats)
{
    __shared__ float ss[8], sq[8];
    int tid = threadIdx.x;
    if (tid < 8) { ss[tid] = 0.f; sq[tid] = 0.f; }
    __syncthreads();
    int gt = blockIdx.x * 256 + tid;
    float s = 0.f, q = 0.f;
    for (int e = gt; e < 32768*8; e += 256*256) { float v = cont[e]; s += v; q += v*v; }
    int f = gt & 7;
    atomicAdd(&ss[f], s);
    atomicAdd(&sq[f], q);
    __syncthreads();
    if (tid < 8) { atomicAdd(&stats[tid], ss[tid]); atomicAdd(&stats[8+tid], sq[tid]); }
}

// ---------------------------------------------------------------------------
// cont path fused: BN-normalize + (8x256 GEMM) + bias + LN + leaky -> bf16
// ---------------------------------------------------------------------------
__global__ __launch_bounds__(256) void cont_k(
    const float* __restrict__ cont, const float* __restrict__ stats,
    const float* __restrict__ bn_g, const float* __restrict__ bn_b,
    const float* __restrict__ W, const float* __restrict__ bias,
    const float* __restrict__ g, const float* __restrict__ bL,
    unsigned short* __restrict__ seq3)
{
    __shared__ float Ws[8][256];
    __shared__ float sscale[8], sshift[8];
    __shared__ float cr[8];
    __shared__ float red[8];
    int tid = threadIdx.x;
    #pragma unroll
    for (int d = 0; d < 8; ++d) Ws[d][tid] = W[d*256 + tid];
    if (tid < 8) {
        float mean = stats[tid] * (1.0f/32768.0f);
        float var  = stats[8+tid] * (1.0f/32768.0f) - mean*mean;
        float r = rsqrtf(var + EPSV);
        float sc = r * bn_g[tid];
        sscale[tid] = sc;
        sshift[tid] = bn_b[tid] - mean*sc;
    }
    __syncthreads();
    int lane = tid & 63, wv = tid >> 6;
    float gv = g[tid], bv = bL[tid], biasv = bias[tid];
    for (int row = blockIdx.x; row < 32768; row += gridDim.x) {
        if (tid < 8) cr[tid] = cont[(size_t)row*8 + tid]*sscale[tid] + sshift[tid];
        __syncthreads();
        float acc = biasv;
        #pragma unroll
        for (int d = 0; d < 8; ++d) acc += cr[d]*Ws[d][tid];
        float s = acc;
        #pragma unroll
        for (int o = 32; o; o >>= 1) s += __shfl_xor(s, o);
        if (lane == 0) red[wv] = s;
        __syncthreads();
        float mu = (red[0]+red[1]+red[2]+red[3]) * (1.0f/256.0f);
        float dc = acc - mu;
        float qv = dc*dc;
        #pragma unroll
        for (int o = 32; o; o >>= 1) qv += __shfl_xor(qv, o);
        if (lane == 0) red[4+wv] = qv;
        __syncthreads();
        float var = (red[4]+red[5]+red[6]+red[7]) * (1.0f/256.0f);
        float y = dc * rsqrtf(var + EPSV) * gv + bv;
        y = (y >= 0.f) ? y : 0.01f*y;
        seq3[(size_t)row*768 + 512 + tid] = f2bf(y);
        __syncthreads();
    }
}

// ---------------------------------------------------------------------------
// key-index construction
// ---------------------------------------------------------------------------
__global__ void build_maps_k(const int* __restrict__ qidx, int* __restrict__ kmap)
{
    __shared__ int flag[1024];
    __shared__ int scan[1024];
    int t = threadIdx.x;
    flag[t] = 0;
    __syncthreads();
    if (t < 128) flag[qidx[t]] = 1;
    __syncthreads();
    int nq = 1 - flag[t];
    scan[t] = nq;
    __syncthreads();
    for (int off = 1; off < 1024; off <<= 1) {
        int v = (t >= off) ? scan[t - off] : 0;
        __syncthreads();
        scan[t] += v;
        __syncthreads();
    }
    if (nq) kmap[scan[t] - 1] = t;
}

__global__ void expand_maps_k(const int* __restrict__ qidx, const int* __restrict__ kmap,
                              int* __restrict__ qmap, int* __restrict__ krmap)
{
    int i = blockIdx.x * 256 + threadIdx.x;
    if (i < 32*128) { int b = i >> 7; int t = i & 127; qmap[i] = b*1024 + qidx[t]; }
    if (i < 32*896) { int b = i / 896; int t = i - b*896; krmap[i] = b*1024 + kmap[t]; }
}

// ---------------------------------------------------------------------------
// mask dtype sniff (parallel): flags[0]=u8 evidence, flags[1]=i32 evidence
// ---------------------------------------------------------------------------
__global__ __launch_bounds__(256) void mask_sniff_k(const unsigned char* __restrict__ msrc,
                                                    int* __restrict__ flags)
{
    int i = blockIdx.x * 256 + threadIdx.x;
    unsigned char v = msrc[i];
    bool u8  = v && (i & 3);
    bool i32 = v && !(i & 3) && ((i & 7) == 4);
    unsigned long long bu = __ballot(u8);
    unsigned long long bi = __ballot(i32);
    if ((threadIdx.x & 63) == 0) {
        if (bu) atomicOr(&flags[0], 1);
        if (bi) atomicOr(&flags[1], 1);
    }
}

__global__ __launch_bounds__(256) void mask_conv_k(const unsigned char* __restrict__ msrc,
                                                   const int* __restrict__ flags,
                                                   unsigned char* __restrict__ mu8)
{
    int i = blockIdx.x * 256 + threadIdx.x;
    int mode = flags[0] ? 0 : (flags[1] ? 1 : 2);
    unsigned char v;
    if (mode == 0)      v = msrc[i] ? 1 : 0;
    else if (mode == 1) v = ((const int*)msrc)[i] ? 1 : 0;
    else                v = ((const long long*)msrc)[i] ? 1 : 0;
    mu8[i] = v;
}

// ---------------------------------------------------------------------------
// MFMA flash attention. Grid 512 = (b, h, qhalf). 4 waves/block.
// ---------------------------------------------------------------------------
__global__ __launch_bounds__(256) void attn_mfma_k(
    const unsigned short* __restrict__ Qb,
    const unsigned short* __restrict__ Kb,
    const unsigned short* __restrict__ Vtb,
    const unsigned char* __restrict__ mask,
    unsigned short* __restrict__ out)
{
    __shared__ unsigned short Pw[4][16][72];
    const int t = threadIdx.x;
    const int w = t >> 6, l = t & 63;
    const int lr = l & 15, lg = l >> 4;
    const int bx = blockIdx.x;
    const int qh = bx & 1, h = (bx >> 1) & 7, b = bx >> 4;
    const int qrow0 = b*128 + qh*64 + w*16;

    short8v qf = *(const short8v*)&Qb[(size_t)(qrow0 + lr)*256 + h*32 + lg*8];

    const unsigned short* Kbase = Kb + (size_t)b*896*256 + h*32;
    const unsigned short* Vbase = Vtb + ((size_t)b*256 + h*32)*896;
    const unsigned char* mrow = mask + b*896;

    float4v O0 = (float4v)0.f, O1 = (float4v)0.f;
    float m[4], lsum[4];
    #pragma unroll
    for (int r = 0; r < 4; ++r) { m[r] = -3.0e38f; lsum[r] = 0.f; }

    short8v kf[4], vf[4];
    int mk[4];
    #pragma unroll
    for (int i = 0; i < 4; ++i) {
        kf[i] = *(const short8v*)&Kbase[(size_t)(i*16 + lr)*256 + lg*8];
        mk[i] = mrow[i*16 + lr];
    }
    #pragma unroll
    for (int kc = 0; kc < 2; ++kc)
        #pragma unroll
        for (int nt = 0; nt < 2; ++nt)
            vf[kc*2+nt] = *(const short8v*)&Vbase[(size_t)(nt*16 + lr)*896 + kc*32 + lg*8];

    for (int kt3 = 0; kt3 < 14; ++kt3) {
        const int kb2 = kt3*64 + 64;
        short8v kf2[4], vf2[4];
        int mk2[4];
        if (kt3 < 13) {
            #pragma unroll
            for (int i = 0; i < 4; ++i) {
                kf2[i] = *(const short8v*)&Kbase[(size_t)(kb2 + i*16 + lr)*256 + lg*8];
                mk2[i] = mrow[kb2 + i*16 + lr];
            }
            #pragma unroll
            for (int kc = 0; kc < 2; ++kc)
                #pragma unroll
                for (int nt = 0; nt < 2; ++nt)
                    vf2[kc*2+nt] = *(const short8v*)&Vbase[(size_t)(nt*16 + lr)*896 + kb2 + kc*32 + lg*8];
        }
        float4v s4[4];
        #pragma unroll
        for (int i = 0; i < 4; ++i)
            s4[i] = __builtin_amdgcn_mfma_f32_16x16x32_bf16(qf, kf[i], (float4v)0.f, 0, 0, 0);
        #pragma unroll
        for (int i = 0; i < 4; ++i)
            #pragma unroll
            for (int r = 0; r < 4; ++r)
                s4[i][r] = mk[i] ? -1e9f : s4[i][r] * 0.17677669529663687f;
        float tm[4];
        #pragma unroll
        for (int r = 0; r < 4; ++r)
            tm[r] = fmaxf(fmaxf(s4[0][r], s4[1][r]), fmaxf(s4[2][r], s4[3][r]));
        #pragma unroll
        for (int o = 1; o < 16; o <<= 1)
            #pragma unroll
            for (int r = 0; r < 4; ++r) tm[r] = fmaxf(tm[r], __shfl_xor(tm[r], o));
        float resc[4];
        #pragma unroll
        for (int r = 0; r < 4; ++r) {
            float mn = fmaxf(m[r], tm[r]);
            resc[r] = __expf(m[r] - mn);
            m[r] = mn;
        }
        float rs[4] = {0.f, 0.f, 0.f, 0.f};
        #pragma unroll
        for (int i = 0; i < 4; ++i)
            #pragma unroll
            for (int r = 0; r < 4; ++r) {
                float p = __expf(s4[i][r] - m[r]);
                s4[i][r] = p;
                rs[r] += p;
            }
        #pragma unroll
        for (int o = 1; o < 16; o <<= 1)
            #pragma unroll
            for (int r = 0; r < 4; ++r) rs[r] += __shfl_xor(rs[r], o);
        #pragma unroll
        for (int r = 0; r < 4; ++r) lsum[r] = lsum[r]*resc[r] + rs[r];
        #pragma unroll
        for (int r = 0; r < 4; ++r) { O0[r] *= resc[r]; O1[r] *= resc[r]; }
        #pragma unroll
        for (int i = 0; i < 4; ++i)
            #pragma unroll
            for (int r = 0; r < 4; ++r)
                Pw[w][lg*4 + r][i*16 + lr] = f2bf(s4[i][r]);
        #pragma unroll
        for (int kc = 0; kc < 2; ++kc) {
            short8v pf = *(const short8v*)&Pw[w][lr][kc*32 + lg*8];
            O0 = __builtin_amdgcn_mfma_f32_16x16x32_bf16(pf, vf[kc*2+0], O0, 0, 0, 0);
            O1 = __builtin_amdgcn_mfma_f32_16x16x32_bf16(pf, vf[kc*2+1], O1, 0, 0, 0);
        }
        if (kt3 < 13) {
            #pragma unroll
            for (int i = 0; i < 4; ++i) { kf[i] = kf2[i]; mk[i] = mk2[i]; vf[i] = vf2[i]; }
        }
    }
    #pragma unroll
    for (int r = 0; r < 4; ++r) {
        float inv = 1.0f / lsum[r];
        size_t row = (size_t)(qrow0 + lg*4 + r);
        out[row*256 + h*32 + lr]      = f2bf(O0[r] * inv);
        out[row*256 + h*32 + 16 + lr] = f2bf(O1[r] * inv);
    }
}

// ---------------------------------------------------------------------------
extern "C" void kernel_launch(void* const* d_in, const int* in_sizes, int n_in,
                              void* d_out, int out_size, void* d_ws, size_t ws_size,
                              hipStream_t stream)
{
    const float* node       = (const float*)d_in[0];
    const int*   cate       = (const int*)d_in[1];
    const float* cont       = (const float*)d_in[2];
    const int*   qidx       = (const int*)d_in[3];
    const unsigned char* mask = (const unsigned char*)d_in[4];
    const float* cate_table = (const float*)d_in[5];
    const float* pos_emb    = (const float*)d_in[6];
    const float* node_W     = (const float*)d_in[7];
    const float* node_b     = (const float*)d_in[8];
    const float* node_ln_g  = (const float*)d_in[9];
    const float* node_ln_b  = (const float*)d_in[10];
    const float* cate_W     = (const float*)d_in[11];
    const float* cate_b     = (const float*)d_in[12];
    const float* cate_ln_g  = (const float*)d_in[13];
    const float* cate_ln_b  = (const float*)d_in[14];
    const float* bn_g       = (const float*)d_in[15];
    const float* bn_b       = (const float*)d_in[16];
    const float* cont_W     = (const float*)d_in[17];
    const float* cont_b     = (const float*)d_in[18];
    const float* cont_ln_g  = (const float*)d_in[19];
    const float* cont_ln_b  = (const float*)d_in[20];
    const float* comb_W     = (const float*)d_in[21];
    const float* comb_b     = (const float*)d_in[22];
    const float* comb_ln_g  = (const float*)d_in[23];
    const float* comb_ln_b  = (const float*)d_in[24];
    const float* q_W        = (const float*)d_in[25];
    const float* q_b        = (const float*)d_in[26];
    const float* k_W        = (const float*)d_in[27];
    const float* k_b        = (const float*)d_in[28];
    const float* v_W        = (const float*)d_in[29];
    const float* v_b        = (const float*)d_in[30];
    const float* reg_W1     = (const float*)d_in[31];
    const float* reg_b1     = (const float*)d_in[32];
    const float* reg_ln_g   = (const float*)d_in[33];
    const float* reg_ln_b   = (const float*)d_in[34];
    const float* reg_W2     = (const float*)d_in[35];
    const float* reg_b2     = (const float*)d_in[36];

    char* ws = (char*)d_ws;
    unsigned short* seq3bf = (unsigned short*)(ws + 0);          // 32768*768*2
    unsigned short* seqbf  = (unsigned short*)(ws + 83886080);   // 32768*256*2
    unsigned short* Qbf    = (unsigned short*)(ws + 100663296);  // 4096*256*2
    unsigned short* Kbf    = (unsigned short*)(ws + 102760448);  // 28672*256*2
    unsigned short* Vtbf   = (unsigned short*)(ws + 117440512);  // 28672*256*2 (transposed)
    unsigned short* AObf   = (unsigned short*)(ws + 132120576);  // 4096*256*2
    unsigned short* Hbf    = (unsigned short*)(ws + 0);          // reuse seq3bf region
    float* stats = (float*)(ws + 165675008);                     // 16 f
    int*   flags = (int*)  (ws + 165675072);                     // 2 i (zeroed with stats)
    int*   kmap  = (int*)  (ws + 165675136);
    int*   qmap  = (int*)  (ws + 165678720);
    int*   krmap = (int*)  (ws + 165695104);
    unsigned char* mu8 = (unsigned char*)(ws + 165809792);
    unsigned short* node_Wt = (unsigned short*)(ws + 165838464);
    unsigned short* cate_Wt = (unsigned short*)(ws + 166362752);
    unsigned short* comb_Wt = (unsigned short*)(ws + 166887040);
    unsigned short* q_Wt    = (unsigned short*)(ws + 167280256);
    unsigned short* k_Wt    = (unsigned short*)(ws + 167411328);
    unsigned short* v_Wt    = (unsigned short*)(ws + 167542400);
    unsigned short* r1_Wt   = (unsigned short*)(ws + 167673472);
    unsigned short* r2_Wt   = (unsigned short*)(ws + 167804544);
    float* outp = (float*)d_out;

    hipMemsetAsync(stats, 0, 128, stream);
    bn_stats_k<<<256, 256, 0, stream>>>(cont, stats);
    mask_sniff_k<<<112, 256, 0, stream>>>(mask, flags);
    mask_conv_k<<<112, 256, 0, stream>>>(mask, flags, mu8);
    wt_all_k<<<256, 256, 0, stream>>>(node_W, cate_W, comb_W, q_W, k_W, v_W, reg_W1, reg_W2,
                                      node_Wt, cate_Wt, comb_Wt, q_Wt, k_Wt, v_Wt, r1_Wt, r2_Wt);

    // node path (GEMM + LN + leaky fused)
    gemm_mfma_k<0,0,3><<<512, 256, 0, stream>>>(32768, 1024, node, nullptr, nullptr, node_Wt,
        node_b, node_ln_g, node_ln_b, nullptr, seq3bf, 768, 0);
    // cate path
    gemm_mfma_k<1,0,3><<<512, 256, 0, stream>>>(32768, 1024, nullptr, cate, cate_table, cate_Wt,
        cate_b, cate_ln_g, cate_ln_b, nullptr, seq3bf, 768, 256);
    // cont path
    cont_k<<<2048,256,0,stream>>>(cont, stats, bn_g, bn_b, cont_W, cont_b, cont_ln_g, cont_ln_b, seq3bf);
    // comb (GEMM + LN + pos fused)
    gemm_mfma_k<0,1,4><<<512, 256, 0, stream>>>(32768, 768, seq3bf, nullptr, nullptr, comb_Wt,
        comb_b, comb_ln_g, comb_ln_b, pos_emb, seqbf, 256, 0);
    // index maps
    build_maps_k<<<1,1024,0,stream>>>(qidx, kmap);
    expand_maps_k<<<112,256,0,stream>>>(qidx, kmap, qmap, krmap);
    // Q/K/V projections -> bf16 (V transposed per head)
    gemm_mfma_k<2,1,1><<<64,  256, 0, stream>>>(4096,  256, seqbf, qmap,  nullptr, q_Wt,
        q_b, nullptr, nullptr, nullptr, Qbf, 256, 0);
    gemm_mfma_k<2,1,1><<<448, 256, 0, stream>>>(28672, 256, seqbf, krmap, nullptr, k_Wt,
        k_b, nullptr, nullptr, nullptr, Kbf, 256, 0);
    gemm_mfma_k<2,1,2><<<448, 256, 0, stream>>>(28672, 256, seqbf, krmap, nullptr, v_Wt,
        v_b, nullptr, nullptr, nullptr, Vtbf, 256, 0);
    // attention (MFMA flash)
    attn_mfma_k<<<512,256,0,stream>>>(Qbf, Kbf, Vtbf, mu8, AObf);
    // regression head
    gemm_mfma_k<0,1,3><<<64, 256, 0, stream>>>(4096, 256, AObf, nullptr, nullptr, r1_Wt,
        reg_b1, reg_ln_g, reg_ln_b, nullptr, Hbf, 256, 0);
    gemm_mfma_k<0,1,0><<<64, 256, 0, stream>>>(4096, 256, Hbf, nullptr, nullptr, r2_Wt,
        reg_b2, nullptr, nullptr, nullptr, outp, 256, 0);
}